// Round 1
// baseline (4678.490 us; speedup 1.0000x reference)
//
#include <hip/hip_runtime.h>
#include <math.h>

#define B_ 16
#define T1_ 65
#define T_ 64
#define S_ 128
#define H_ 512
#define G_ 1536   /* 3H */
#define V_ 32000

// ---------------- K0: xg[b,t,g] = dot(emb[tok], W_ih[g,:]) + b_ih[g] ----------------
__global__ __launch_bounds__(256) void k_embed_xg(
    const int* __restrict__ inputs, const float* __restrict__ emb,
    const float* __restrict__ W_ih, const float* __restrict__ b_ih,
    float* __restrict__ xg) {
  __shared__ float xrow[H_];
  int row = blockIdx.x;            // b*T + t
  int b = row >> 6, t = row & 63;
  int tok = inputs[b * T1_ + t];   // dec_in = inputs[:, :-1]
  const float* e = emb + (size_t)tok * H_;
  for (int i = threadIdx.x; i < H_; i += 256) xrow[i] = e[i];
  __syncthreads();
  int g = blockIdx.y * 256 + threadIdx.x;
  const float4* w4 = (const float4*)(W_ih + (size_t)g * H_);
  const float4* x4 = (const float4*)xrow;
  float acc = 0.f;
#pragma unroll 8
  for (int k = 0; k < H_ / 4; ++k) {
    float4 w = w4[k], x = x4[k];
    acc += w.x * x.x + w.y * x.y + w.z * x.z + w.w * x.w;
  }
  xg[(size_t)row * G_ + g] = acc + b_ih[g];
}

// ---------------- GRU step t ----------------
__global__ __launch_bounds__(256) void k_gru_step(
    const float* __restrict__ hprev, int hstride,
    const float* __restrict__ xg, int t,
    const float* __restrict__ W_hh, const float* __restrict__ b_hh,
    float* __restrict__ gru_out) {
  __shared__ float h[H_];
  int b = blockIdx.x >> 1;
  int j = ((blockIdx.x & 1) << 8) + threadIdx.x;
  const float* hp = hprev + (size_t)b * hstride;
  for (int i = threadIdx.x; i < H_; i += 256) h[i] = hp[i];
  __syncthreads();
  const float4* h4 = (const float4*)h;
  const float4* wr = (const float4*)(W_hh + (size_t)j * H_);
  const float4* wz = (const float4*)(W_hh + (size_t)(j + H_) * H_);
  const float4* wn = (const float4*)(W_hh + (size_t)(j + 2 * H_) * H_);
  float ar = 0.f, az = 0.f, an = 0.f;
#pragma unroll 4
  for (int k = 0; k < H_ / 4; ++k) {
    float4 hv = h4[k];
    float4 a = wr[k]; ar += a.x * hv.x + a.y * hv.y + a.z * hv.z + a.w * hv.w;
    float4 c = wz[k]; az += c.x * hv.x + c.y * hv.y + c.z * hv.z + c.w * hv.w;
    float4 d = wn[k]; an += d.x * hv.x + d.y * hv.y + d.z * hv.z + d.w * hv.w;
  }
  ar += b_hh[j]; az += b_hh[H_ + j]; an += b_hh[2 * H_ + j];
  const float* xgt = xg + (size_t)(b * T_ + t) * G_;
  float xr = xgt[j], xz = xgt[H_ + j], xn = xgt[2 * H_ + j];
  float r = 1.f / (1.f + expf(-(xr + ar)));
  float z = 1.f / (1.f + expf(-(xz + az)));
  float n = tanhf(xn + r * an);
  float hnew = (1.f - z) * n + z * h[j];
  gru_out[((size_t)b * T_ + t) * H_ + j] = hnew;
}

// ---------------- copy h_last ----------------
__global__ __launch_bounds__(256) void k_hlast(const float* __restrict__ gru_out,
                                               float* __restrict__ hlast) {
  int i = blockIdx.x * 256 + threadIdx.x;  // 8192
  int b = i >> 9, j = i & 511;
  hlast[i] = gru_out[((size_t)b * T_ + (T_ - 1)) * H_ + j];
}

// ---------------- attention: scores -> softmax -> mix -> combined ----------------
__global__ __launch_bounds__(256) void k_attn(
    const float* __restrict__ gru_out, const float* __restrict__ enc,
    float* __restrict__ attn_out, float* __restrict__ combined) {
  __shared__ float orow[H_];
  __shared__ float sc[S_];
  __shared__ float red[S_];
  int row = blockIdx.x;  // b*T + t
  int b = row >> 6;
  int tid = threadIdx.x;
  const float* o = gru_out + (size_t)row * H_;
  for (int i = tid; i < H_; i += 256) orow[i] = o[i];
  __syncthreads();
  if (tid < S_) {
    const float4* e4 = (const float4*)(enc + ((size_t)b * S_ + tid) * H_);
    const float4* o4 = (const float4*)orow;
    float acc = 0.f;
#pragma unroll 8
    for (int k = 0; k < H_ / 4; ++k) {
      float4 e = e4[k], x = o4[k];
      acc += e.x * x.x + e.y * x.y + e.z * x.z + e.w * x.w;
    }
    sc[tid] = acc; red[tid] = acc;
  }
  __syncthreads();
  for (int s = 64; s > 0; s >>= 1) {
    if (tid < s) red[tid] = fmaxf(red[tid], red[tid + s]);
    __syncthreads();
  }
  float m = red[0];
  __syncthreads();
  if (tid < S_) { float p = expf(sc[tid] - m); sc[tid] = p; red[tid] = p; }
  __syncthreads();
  for (int s = 64; s > 0; s >>= 1) {
    if (tid < s) red[tid] += red[tid + s];
    __syncthreads();
  }
  float inv = 1.f / red[0];
  __syncthreads();
  if (tid < S_) {
    float a = sc[tid] * inv;
    sc[tid] = a;
    attn_out[(size_t)row * S_ + tid] = a;
  }
  __syncthreads();
  // mix[h] = sum_s a[s] * enc[b,s,h]  ; thread covers h=tid and h=tid+256
  float acc0 = 0.f, acc1 = 0.f;
  for (int s = 0; s < S_; ++s) {
    float a = sc[s];
    const float* e = enc + ((size_t)b * S_ + s) * H_;
    acc0 += a * e[tid];
    acc1 += a * e[tid + 256];
  }
  float* crow = combined + (size_t)row * (2 * H_);
  crow[tid] = acc0;
  crow[256 + tid] = acc1;
  crow[512 + tid] = orow[tid];
  crow[768 + tid] = orow[tid + 256];
}

// ---------------- out2 = tanh(combined @ attn_W^T + attn_b) ----------------
__global__ __launch_bounds__(256) void k_attnproj(
    const float* __restrict__ combined, const float* __restrict__ attn_W,
    const float* __restrict__ attn_b, float* __restrict__ out2) {
  __shared__ float c[16 * 1024];  // 64 KB
  int row0 = blockIdx.y * 16;
  const float4* src = (const float4*)(combined + (size_t)row0 * (2 * H_));
  float4* d4 = (float4*)c;
  for (int i = threadIdx.x; i < 16 * 256; i += 256) d4[i] = src[i];
  __syncthreads();
  int hcol = blockIdx.x * 256 + threadIdx.x;
  const float4* w4 = (const float4*)(attn_W + (size_t)hcol * (2 * H_));
  float acc[16];
#pragma unroll
  for (int r = 0; r < 16; ++r) acc[r] = 0.f;
  for (int k = 0; k < 256; ++k) {
    float4 w = w4[k];
#pragma unroll
    for (int r = 0; r < 16; ++r) {
      float4 cv = ((const float4*)(c + r * 1024))[k];
      acc[r] += w.x * cv.x + w.y * cv.y + w.z * cv.z + w.w * cv.w;
    }
  }
  float bias = attn_b[hcol];
#pragma unroll
  for (int r = 0; r < 16; ++r)
    out2[(size_t)(row0 + r) * H_ + hcol] = tanhf(acc[r] + bias);
}

// ---------------- logits = out2 @ out_W^T + out_b  (into d_out log_probs region) ----------------
__global__ __launch_bounds__(256) void k_logits(
    const float* __restrict__ out2, const float* __restrict__ out_W,
    const float* __restrict__ out_b, float* __restrict__ logits) {
  __shared__ float o[32 * 512];  // 64 KB
  int row0 = blockIdx.y * 32;
  const float4* src = (const float4*)(out2 + (size_t)row0 * H_);
  float4* d4 = (float4*)o;
  for (int i = threadIdx.x; i < 32 * 128; i += 256) d4[i] = src[i];
  __syncthreads();
  int v = blockIdx.x * 256 + threadIdx.x;
  const float4* w4 = (const float4*)(out_W + (size_t)v * H_);
  float acc[32];
#pragma unroll
  for (int r = 0; r < 32; ++r) acc[r] = 0.f;
  for (int k = 0; k < 128; ++k) {
    float4 w = w4[k];
#pragma unroll
    for (int r = 0; r < 32; ++r) {
      float4 cv = ((const float4*)(o + r * 512))[k];
      acc[r] += w.x * cv.x + w.y * cv.y + w.z * cv.z + w.w * cv.w;
    }
  }
  float bias = out_b[v];
#pragma unroll
  for (int r = 0; r < 32; ++r)
    logits[(size_t)(row0 + r) * V_ + v] = acc[r] + bias;
}

// ---------------- in-place log_softmax over V per row ----------------
__global__ __launch_bounds__(1024) void k_logsoftmax(float* __restrict__ logits) {
  int row = blockIdx.x;
  float* x = logits + (size_t)row * V_;
  int tid = threadIdx.x;
  float m = -INFINITY, s = 0.f;
  for (int i = tid; i < V_; i += 1024) {
    float v = x[i];
    float mn = fmaxf(m, v);
    s = s * expf(m - mn) + expf(v - mn);
    m = mn;
  }
  __shared__ float sm[1024], ss[1024];
  sm[tid] = m; ss[tid] = s;
  __syncthreads();
  for (int st = 512; st > 0; st >>= 1) {
    if (tid < st) {
      float m2 = sm[tid + st], s2 = ss[tid + st];
      float mn = fmaxf(sm[tid], m2);
      ss[tid] = ss[tid] * expf(sm[tid] - mn) + s2 * expf(m2 - mn);
      sm[tid] = mn;
    }
    __syncthreads();
  }
  float L = logf(ss[0]) + sm[0];
  for (int i = tid; i < V_; i += 1024) x[i] = x[i] - L;
}

extern "C" void kernel_launch(void* const* d_in, const int* in_sizes, int n_in,
                              void* d_out, int out_size, void* d_ws, size_t ws_size,
                              hipStream_t stream) {
  const int*   inputs  = (const int*)d_in[0];
  const float* enc_h   = (const float*)d_in[1];   // (1,B,H)
  const float* enc_out = (const float*)d_in[2];   // (B,S,H)
  const float* emb     = (const float*)d_in[3];
  const float* W_ih    = (const float*)d_in[4];
  const float* W_hh    = (const float*)d_in[5];
  const float* b_ih    = (const float*)d_in[6];
  const float* b_hh    = (const float*)d_in[7];
  const float* attn_W  = (const float*)d_in[8];
  const float* attn_b  = (const float*)d_in[9];
  const float* out_W   = (const float*)d_in[10];
  const float* out_b   = (const float*)d_in[11];

  float* out       = (float*)d_out;
  float* log_probs = out;                                  // B*T*V
  float* hlast     = out + (size_t)B_ * T_ * V_;           // B*H
  float* attn      = hlast + B_ * H_;                      // B*T*S

  float* ws       = (float*)d_ws;
  float* xg       = ws;                 // 1,572,864 floats (aliased below after scan)
  float* combined = ws;                 // 1,048,576 floats (reuses xg space)
  float* out2     = ws + 1048576;       //   524,288 floats
  float* gru_out  = ws + 1572864;       //   524,288 floats

  k_embed_xg<<<dim3(1024, 6), 256, 0, stream>>>(inputs, emb, W_ih, b_ih, xg);

  for (int t = 0; t < T_; ++t) {
    const float* hprev = (t == 0) ? enc_h : (gru_out + (size_t)(t - 1) * H_);
    int hstride = (t == 0) ? H_ : T_ * H_;
    k_gru_step<<<32, 256, 0, stream>>>(hprev, hstride, xg, t, W_hh, b_hh, gru_out);
  }

  k_hlast<<<32, 256, 0, stream>>>(gru_out, hlast);
  k_attn<<<1024, 256, 0, stream>>>(gru_out, enc_out, attn, combined);
  k_attnproj<<<dim3(2, 64), 256, 0, stream>>>(combined, attn_W, attn_b, out2);
  k_logits<<<dim3(125, 32), 256, 0, stream>>>(out2, out_W, out_b, log_probs);
  k_logsoftmax<<<1024, 1024, 0, stream>>>(log_probs);
}

// Round 2
// 2260.297 us; speedup vs baseline: 2.0699x; 2.0699x over previous
//
#include <hip/hip_runtime.h>
#include <math.h>

#define B_ 16
#define T1_ 65
#define T_ 64
#define S_ 128
#define H_ 512
#define G_ 1536   /* 3H */
#define V_ 32000

typedef float f32x4 __attribute__((ext_vector_type(4)));
typedef __bf16 bf16x8 __attribute__((ext_vector_type(8)));
typedef short s16x4 __attribute__((ext_vector_type(4)));

__device__ inline unsigned short f2bf(float f) {
  union { float f; unsigned u; } x; x.f = f;
  unsigned r = x.u + 0x7fff + ((x.u >> 16) & 1);  // RNE
  return (unsigned short)(r >> 16);
}

// ---------------- gather X[row] = emb[tok] ----------------
__global__ __launch_bounds__(128) void k_gather(
    const int* __restrict__ inputs, const float* __restrict__ emb,
    float* __restrict__ X) {
  int row = blockIdx.x;            // b*T + t
  int b = row >> 6, t = row & 63;
  int tok = inputs[b * T1_ + t];   // dec_in = inputs[:, :-1]
  float4 v = ((const float4*)(emb + (size_t)tok * H_))[threadIdx.x];
  ((float4*)(X + (size_t)row * H_))[threadIdx.x] = v;
}

// ---------------- generic MFMA GEMM: C = act(A[M,K] @ W[N,K]^T + bias) ----------------
// fp32 in/out, bf16 convert-on-stage, 128x128 tile, BK=64, 4 waves (2x2 of 64x64),
// XOR-swizzled LDS (T2): byte ^= (row&7)<<4 to kill the stride-128B bank conflict.
template <int TANH>
__global__ __launch_bounds__(256) void k_gemm(
    const float* __restrict__ A, const float* __restrict__ W,
    const float* __restrict__ bias, float* __restrict__ C,
    int M, int N, int K) {
  __shared__ char sA[128 * 64 * 2];   // 16 KB bf16
  __shared__ char sB[128 * 64 * 2];
  int tid = threadIdx.x;
  int m0 = blockIdx.x * 128, n0 = blockIdx.y * 128;
  int lane = tid & 63, wave = tid >> 6;
  int wm = wave >> 1, wn = wave & 1;
  int lr = lane & 15, kg = lane >> 4;
  f32x4 acc[4][4] = {};

  for (int kk = 0; kk < K; kk += 64) {
    __syncthreads();
    // stage both tiles: 128 rows x 16 float4-chunks = 2048 chunks, 8 per thread
#pragma unroll
    for (int i = 0; i < 8; ++i) {
      int idx = tid + i * 256;
      int row = idx >> 4, kq = idx & 15;
      float4 va = *(const float4*)(A + (size_t)(m0 + row) * K + kk + kq * 4);
      float4 vb = *(const float4*)(W + (size_t)(n0 + row) * K + kk + kq * 4);
      int byte = (row * 128 + kq * 8) ^ ((row & 7) << 4);
      s16x4 pa; pa[0] = (short)f2bf(va.x); pa[1] = (short)f2bf(va.y);
      pa[2] = (short)f2bf(va.z); pa[3] = (short)f2bf(va.w);
      s16x4 pb; pb[0] = (short)f2bf(vb.x); pb[1] = (short)f2bf(vb.y);
      pb[2] = (short)f2bf(vb.z); pb[3] = (short)f2bf(vb.w);
      *(s16x4*)(sA + byte) = pa;
      *(s16x4*)(sB + byte) = pb;
    }
    __syncthreads();
#pragma unroll
    for (int ks = 0; ks < 2; ++ks) {
      bf16x8 af[4], bfr[4];
#pragma unroll
      for (int i = 0; i < 4; ++i) {
        int ra = wm * 64 + i * 16 + lr;
        af[i] = *(const bf16x8*)(sA + ((ra * 128 + ks * 64 + kg * 16) ^ ((ra & 7) << 4)));
        int rb = wn * 64 + i * 16 + lr;
        bfr[i] = *(const bf16x8*)(sB + ((rb * 128 + ks * 64 + kg * 16) ^ ((rb & 7) << 4)));
      }
#pragma unroll
      for (int mi = 0; mi < 4; ++mi)
#pragma unroll
        for (int ni = 0; ni < 4; ++ni)
          acc[mi][ni] = __builtin_amdgcn_mfma_f32_16x16x32_bf16(
              af[mi], bfr[ni], acc[mi][ni], 0, 0, 0);
    }
  }
  // epilogue: C/D layout col=lane&15, row=(lane>>4)*4+reg  [m89-verified]
#pragma unroll
  for (int ni = 0; ni < 4; ++ni) {
    int col = n0 + wn * 64 + ni * 16 + lr;
    float bv = bias[col];
#pragma unroll
    for (int mi = 0; mi < 4; ++mi) {
      int rbase = m0 + wm * 64 + mi * 16 + kg * 4;
#pragma unroll
      for (int j = 0; j < 4; ++j) {
        float v = acc[mi][ni][j] + bv;
        if (TANH) v = tanhf(v);
        C[(size_t)(rbase + j) * N + col] = v;
      }
    }
  }
}

// ---------------- GRU step t: 64 blocks x 384 threads ----------------
// Block owns 8 cols; thread (b,g,c) computes one 512-dot. W rows shared across batch.
__global__ __launch_bounds__(384) void k_gru_step(
    const float* __restrict__ hprev, int hstride,
    const float* __restrict__ xg, int t,
    const float* __restrict__ W_hh, const float* __restrict__ b_hh,
    float* __restrict__ gru_out) {
  __shared__ float h[16][512];     // 32 KB
  __shared__ float pre[24][16];    // [g*8+c][b]
  int tid = threadIdx.x;
  for (int i = tid; i < 2048; i += 384) {
    int b = i >> 7, k4 = i & 127;
    float4 v = *(const float4*)(hprev + (size_t)b * hstride + k4 * 4);
    *(float4*)(&h[b][k4 * 4]) = v;
  }
  __syncthreads();
  int c = tid & 7, g = (tid >> 3) % 3, b = tid / 24;  // tid = b*24 + g*8 + c
  int col0 = blockIdx.x * 8;
  int row = g * 512 + col0 + c;
  const float4* w4 = (const float4*)(W_hh + (size_t)row * 512);
  const float4* h4 = (const float4*)(&h[b][0]);
  float acc = 0.f;
#pragma unroll 8
  for (int k = 0; k < 128; ++k) {
    float4 w = w4[k], x = h4[k];
    acc += w.x * x.x + w.y * x.y + w.z * x.z + w.w * x.w;
  }
  pre[g * 8 + c][b] = acc + b_hh[row];
  __syncthreads();
  if (tid < 128) {
    int b2 = tid >> 3, c2 = tid & 7;
    int col = col0 + c2;
    const float* xgt = xg + (size_t)(b2 * T_ + t) * G_;
    float r = 1.f / (1.f + expf(-(xgt[col] + pre[c2][b2])));
    float z = 1.f / (1.f + expf(-(xgt[H_ + col] + pre[8 + c2][b2])));
    float n = tanhf(xgt[2 * H_ + col] + r * pre[16 + c2][b2]);
    gru_out[((size_t)b2 * T_ + t) * H_ + col] = (1.f - z) * n + z * h[b2][col];
  }
}

// ---------------- copy h_last ----------------
__global__ __launch_bounds__(256) void k_hlast(const float* __restrict__ gru_out,
                                               float* __restrict__ hlast) {
  int i = blockIdx.x * 256 + threadIdx.x;  // 8192
  int b = i >> 9, j = i & 511;
  hlast[i] = gru_out[((size_t)b * T_ + (T_ - 1)) * H_ + j];
}

// ---------------- attention: scores -> softmax -> mix -> combined ----------------
__global__ __launch_bounds__(256) void k_attn(
    const float* __restrict__ gru_out, const float* __restrict__ enc,
    float* __restrict__ attn_out, float* __restrict__ combined) {
  __shared__ float orow[H_];
  __shared__ float sc[S_];
  __shared__ float red[S_];
  int row = blockIdx.x;  // b*T + t
  int b = row >> 6;
  int tid = threadIdx.x;
  const float* o = gru_out + (size_t)row * H_;
  for (int i = tid; i < H_; i += 256) orow[i] = o[i];
  __syncthreads();
  if (tid < S_) {
    const float4* e4 = (const float4*)(enc + ((size_t)b * S_ + tid) * H_);
    const float4* o4 = (const float4*)orow;
    float acc = 0.f;
#pragma unroll 8
    for (int k = 0; k < H_ / 4; ++k) {
      float4 e = e4[k], x = o4[k];
      acc += e.x * x.x + e.y * x.y + e.z * x.z + e.w * x.w;
    }
    sc[tid] = acc; red[tid] = acc;
  }
  __syncthreads();
  for (int s = 64; s > 0; s >>= 1) {
    if (tid < s) red[tid] = fmaxf(red[tid], red[tid + s]);
    __syncthreads();
  }
  float m = red[0];
  __syncthreads();
  if (tid < S_) { float p = expf(sc[tid] - m); sc[tid] = p; red[tid] = p; }
  __syncthreads();
  for (int s = 64; s > 0; s >>= 1) {
    if (tid < s) red[tid] += red[tid + s];
    __syncthreads();
  }
  float inv = 1.f / red[0];
  __syncthreads();
  if (tid < S_) {
    float a = sc[tid] * inv;
    sc[tid] = a;
    attn_out[(size_t)row * S_ + tid] = a;
  }
  __syncthreads();
  float acc0 = 0.f, acc1 = 0.f;
  for (int s = 0; s < S_; ++s) {
    float a = sc[s];
    const float* e = enc + ((size_t)b * S_ + s) * H_;
    acc0 += a * e[tid];
    acc1 += a * e[tid + 256];
  }
  float* crow = combined + (size_t)row * (2 * H_);
  crow[tid] = acc0;
  crow[256 + tid] = acc1;
  crow[512 + tid] = orow[tid];
  crow[768 + tid] = orow[tid + 256];
}

// ---------------- in-place log_softmax over V per row ----------------
__global__ __launch_bounds__(1024) void k_logsoftmax(float* __restrict__ logits) {
  int row = blockIdx.x;
  float* x = logits + (size_t)row * V_;
  int tid = threadIdx.x;
  float m = -INFINITY, s = 0.f;
  for (int i = tid; i < V_; i += 1024) {
    float v = x[i];
    float mn = fmaxf(m, v);
    s = s * expf(m - mn) + expf(v - mn);
    m = mn;
  }
  __shared__ float sm[1024], ss[1024];
  sm[tid] = m; ss[tid] = s;
  __syncthreads();
  for (int st = 512; st > 0; st >>= 1) {
    if (tid < st) {
      float m2 = sm[tid + st], s2 = ss[tid + st];
      float mn = fmaxf(sm[tid], m2);
      ss[tid] = ss[tid] * expf(sm[tid] - mn) + s2 * expf(m2 - mn);
      sm[tid] = mn;
    }
    __syncthreads();
  }
  float L = logf(ss[0]) + sm[0];
  for (int i = tid; i < V_; i += 1024) x[i] = x[i] - L;
}

extern "C" void kernel_launch(void* const* d_in, const int* in_sizes, int n_in,
                              void* d_out, int out_size, void* d_ws, size_t ws_size,
                              hipStream_t stream) {
  const int*   inputs  = (const int*)d_in[0];
  const float* enc_h   = (const float*)d_in[1];   // (1,B,H)
  const float* enc_out = (const float*)d_in[2];   // (B,S,H)
  const float* emb     = (const float*)d_in[3];
  const float* W_ih    = (const float*)d_in[4];
  const float* W_hh    = (const float*)d_in[5];
  const float* b_ih    = (const float*)d_in[6];
  const float* b_hh    = (const float*)d_in[7];
  const float* attn_W  = (const float*)d_in[8];
  const float* attn_b  = (const float*)d_in[9];
  const float* out_W   = (const float*)d_in[10];
  const float* out_b   = (const float*)d_in[11];

  float* out       = (float*)d_out;
  float* log_probs = out;                                  // B*T*V
  float* hlast     = out + (size_t)B_ * T_ * V_;           // B*H
  float* attn      = hlast + B_ * H_;                      // B*T*S

  // ws layout (floats), total 2,097,152 floats = 8 MB (same footprint as round 1):
  //   X        [0,        524288)   — dead after xg GEMM
  //   xg       [524288,   2097152)  — dead after GRU scan
  //   gru_out  [0,        524288)   — reuses X
  //   combined [524288,   1572864)  — reuses xg head
  //   out2     [1572864,  2097152)  — reuses xg tail
  float* ws       = (float*)d_ws;
  float* X        = ws;
  float* xg       = ws + 524288;
  float* gru_out  = ws;
  float* combined = ws + 524288;
  float* out2     = ws + 1572864;

  k_gather<<<1024, 128, 0, stream>>>(inputs, emb, X);
  k_gemm<0><<<dim3(8, 12), 256, 0, stream>>>(X, W_ih, b_ih, xg, 1024, G_, H_);

  for (int t = 0; t < T_; ++t) {
    const float* hprev = (t == 0) ? enc_h : (gru_out + (size_t)(t - 1) * H_);
    int hstride = (t == 0) ? H_ : T_ * H_;
    k_gru_step<<<64, 384, 0, stream>>>(hprev, hstride, xg, t, W_hh, b_hh, gru_out);
  }

  k_hlast<<<32, 256, 0, stream>>>(gru_out, hlast);
  k_attn<<<1024, 256, 0, stream>>>(gru_out, enc_out, attn, combined);
  k_gemm<1><<<dim3(8, 4), 256, 0, stream>>>(combined, attn_W, attn_b, out2, 1024, H_, 2 * H_);
  k_gemm<0><<<dim3(8, 250), 256, 0, stream>>>(out2, out_W, out_b, log_probs, 1024, V_, H_);
  k_logsoftmax<<<1024, 1024, 0, stream>>>(log_probs);
}

// Round 3
// 1127.703 us; speedup vs baseline: 4.1487x; 2.0043x over previous
//
#include <hip/hip_runtime.h>
#include <math.h>

#define B_ 16
#define T1_ 65
#define T_ 64
#define S_ 128
#define H_ 512
#define G_ 1536   /* 3H */
#define V_ 32000
#define NBLK_GRU 64

typedef float f32x4 __attribute__((ext_vector_type(4)));
typedef __bf16 bf16x8 __attribute__((ext_vector_type(8)));
typedef __bf16 bf16x4 __attribute__((ext_vector_type(4)));
typedef short s16x4 __attribute__((ext_vector_type(4)));
typedef unsigned int u32;

__device__ __forceinline__ void gload16(const void* g, void* l) {
  __builtin_amdgcn_global_load_lds(
      (const __attribute__((address_space(1))) u32*)g,
      (__attribute__((address_space(3))) u32*)l, 16, 0, 0);
}

__device__ inline unsigned short f2bf(float f) {
  union { float f; unsigned u; } x; x.f = f;
  unsigned r = x.u + 0x7fff + ((x.u >> 16) & 1);  // RNE
  return (unsigned short)(r >> 16);
}

// ---------------- zero the grid barrier ----------------
__global__ void k_zero(u32* bar) {
  if (threadIdx.x < 2) bar[threadIdx.x] = 0u;
}

// ---------------- fp32 -> bf16 cast (n4 = n/4) ----------------
__global__ __launch_bounds__(256) void k_cast(const float* __restrict__ src,
                                              __bf16* __restrict__ dst, int n4) {
  int stride = gridDim.x * 256;
  for (int i = blockIdx.x * 256 + threadIdx.x; i < n4; i += stride) {
    float4 v = ((const float4*)src)[i];
    bf16x4 o = {(__bf16)v.x, (__bf16)v.y, (__bf16)v.z, (__bf16)v.w};
    ((bf16x4*)dst)[i] = o;
  }
}

// ---------------- gather X[row] = emb[tok] (bf16 out) ----------------
__global__ __launch_bounds__(128) void k_gather_bf(
    const int* __restrict__ inputs, const float* __restrict__ emb,
    __bf16* __restrict__ Xb) {
  int row = blockIdx.x;            // b*T + t
  int b = row >> 6, t = row & 63;
  int tok = inputs[b * T1_ + t];   // dec_in = inputs[:, :-1]
  float4 v = ((const float4*)(emb + (size_t)tok * H_))[threadIdx.x];
  bf16x4 o = {(__bf16)v.x, (__bf16)v.y, (__bf16)v.z, (__bf16)v.w};
  ((bf16x4*)(Xb + (size_t)row * H_))[threadIdx.x] = o;
}

// ---------------- gather X[row] = emb[tok] (fp32 out, legacy) ----------------
__global__ __launch_bounds__(128) void k_gather32(
    const int* __restrict__ inputs, const float* __restrict__ emb,
    float* __restrict__ X) {
  int row = blockIdx.x;
  int b = row >> 6, t = row & 63;
  int tok = inputs[b * T1_ + t];
  float4 v = ((const float4*)(emb + (size_t)tok * H_))[threadIdx.x];
  ((float4*)(X + (size_t)row * H_))[threadIdx.x] = v;
}

// ---------------- bf16 MFMA GEMM: C = act(A[M,K] @ W[N,K]^T + bias) ----------------
// global_load_lds(16B) staging, T2 XOR-swizzle via pre-swizzled global source.
// 128x128 tile, BK=64, 4 waves (2x2 of 64x64).
template <int TANH, int WF32, int WBF16>
__global__ __launch_bounds__(256) void k_gemm_bf16(
    const __bf16* __restrict__ A, const __bf16* __restrict__ W,
    const float* __restrict__ bias, float* __restrict__ C,
    __bf16* __restrict__ Cb, int M, int N, int K, int mb, int xcdmap) {
  __shared__ __align__(1024) char sA[16384];
  __shared__ __align__(1024) char sB[16384];
  int tid = threadIdx.x;
  int d = blockIdx.x, m_blk, n_blk;
  if (xcdmap) {
    int q = d >> 6, r = d & 63;
    m_blk = r >> 3; n_blk = q * 8 + (r & 7);
    if (n_blk * 128 >= N) return;
  } else {
    m_blk = d % mb; n_blk = d / mb;
  }
  int m0 = m_blk * 128, n0 = n_blk * 128;
  int lane = tid & 63, wave = tid >> 6;
  int wm = wave >> 1, wn = wave & 1;
  int lr = lane & 15, kg = lane >> 4;
  int lrow = lane >> 3, lcp = lane & 7;   // staging: row-in-chunk, phys col granule
  f32x4 acc[4][4] = {};

  for (int kk = 0; kk < K; kk += 64) {
    __syncthreads();
#pragma unroll
    for (int i = 0; i < 4; ++i) {
      int c = wave * 4 + i;             // 16 chunks of 1KB per tile
      int row = c * 8 + lrow;
      int cgl = lcp ^ (row & 7);        // pre-swizzled global source granule
      gload16(A + (size_t)(m0 + row) * K + kk + cgl * 8, sA + c * 1024 + lane * 16);
      gload16(W + (size_t)(n0 + row) * K + kk + cgl * 8, sB + c * 1024 + lane * 16);
    }
    __syncthreads();
#pragma unroll
    for (int ks = 0; ks < 2; ++ks) {
      bf16x8 af[4], bfr[4];
#pragma unroll
      for (int i = 0; i < 4; ++i) {
        int ra = wm * 64 + i * 16 + lr;
        af[i] = *(const bf16x8*)(sA + ra * 128 + ((ks * 64 + kg * 16) ^ ((ra & 7) << 4)));
        int rb = wn * 64 + i * 16 + lr;
        bfr[i] = *(const bf16x8*)(sB + rb * 128 + ((ks * 64 + kg * 16) ^ ((rb & 7) << 4)));
      }
#pragma unroll
      for (int mi = 0; mi < 4; ++mi)
#pragma unroll
        for (int ni = 0; ni < 4; ++ni)
          acc[mi][ni] = __builtin_amdgcn_mfma_f32_16x16x32_bf16(
              af[mi], bfr[ni], acc[mi][ni], 0, 0, 0);
    }
  }
  // epilogue: C/D layout col=lane&15, row=(lane>>4)*4+reg
#pragma unroll
  for (int ni = 0; ni < 4; ++ni) {
    int col = n0 + wn * 64 + ni * 16 + lr;
    float bv = bias[col];
#pragma unroll
    for (int mi = 0; mi < 4; ++mi) {
      int rbase = m0 + wm * 64 + mi * 16 + kg * 4;
#pragma unroll
      for (int j = 0; j < 4; ++j) {
        float v = acc[mi][ni][j] + bv;
        if (TANH) v = tanhf(v);
        if (WF32) C[(size_t)(rbase + j) * N + col] = v;
        if (WBF16) Cb[(size_t)(rbase + j) * N + col] = (__bf16)v;
      }
    }
  }
}

// ---------------- legacy fp32-staging MFMA GEMM (round-2) ----------------
template <int TANH>
__global__ __launch_bounds__(256) void k_gemm(
    const float* __restrict__ A, const float* __restrict__ W,
    const float* __restrict__ bias, float* __restrict__ C,
    int M, int N, int K) {
  __shared__ char sA[128 * 64 * 2];
  __shared__ char sB[128 * 64 * 2];
  int tid = threadIdx.x;
  int m0 = blockIdx.x * 128, n0 = blockIdx.y * 128;
  int lane = tid & 63, wave = tid >> 6;
  int wm = wave >> 1, wn = wave & 1;
  int lr = lane & 15, kg = lane >> 4;
  f32x4 acc[4][4] = {};
  for (int kk = 0; kk < K; kk += 64) {
    __syncthreads();
#pragma unroll
    for (int i = 0; i < 8; ++i) {
      int idx = tid + i * 256;
      int row = idx >> 4, kq = idx & 15;
      float4 va = *(const float4*)(A + (size_t)(m0 + row) * K + kk + kq * 4);
      float4 vb = *(const float4*)(W + (size_t)(n0 + row) * K + kk + kq * 4);
      int byte = (row * 128 + kq * 8) ^ ((row & 7) << 4);
      s16x4 pa; pa[0] = (short)f2bf(va.x); pa[1] = (short)f2bf(va.y);
      pa[2] = (short)f2bf(va.z); pa[3] = (short)f2bf(va.w);
      s16x4 pb; pb[0] = (short)f2bf(vb.x); pb[1] = (short)f2bf(vb.y);
      pb[2] = (short)f2bf(vb.z); pb[3] = (short)f2bf(vb.w);
      *(s16x4*)(sA + byte) = pa;
      *(s16x4*)(sB + byte) = pb;
    }
    __syncthreads();
#pragma unroll
    for (int ks = 0; ks < 2; ++ks) {
      bf16x8 af[4], bfr[4];
#pragma unroll
      for (int i = 0; i < 4; ++i) {
        int ra = wm * 64 + i * 16 + lr;
        af[i] = *(const bf16x8*)(sA + ((ra * 128 + ks * 64 + kg * 16) ^ ((ra & 7) << 4)));
        int rb = wn * 64 + i * 16 + lr;
        bfr[i] = *(const bf16x8*)(sB + ((rb * 128 + ks * 64 + kg * 16) ^ ((rb & 7) << 4)));
      }
#pragma unroll
      for (int mi = 0; mi < 4; ++mi)
#pragma unroll
        for (int ni = 0; ni < 4; ++ni)
          acc[mi][ni] = __builtin_amdgcn_mfma_f32_16x16x32_bf16(
              af[mi], bfr[ni], acc[mi][ni], 0, 0, 0);
    }
  }
#pragma unroll
  for (int ni = 0; ni < 4; ++ni) {
    int col = n0 + wn * 64 + ni * 16 + lr;
    float bv = bias[col];
#pragma unroll
    for (int mi = 0; mi < 4; ++mi) {
      int rbase = m0 + wm * 64 + mi * 16 + kg * 4;
#pragma unroll
      for (int j = 0; j < 4; ++j) {
        float v = acc[mi][ni][j] + bv;
        if (TANH) v = tanhf(v);
        C[(size_t)(rbase + j) * N + col] = v;
      }
    }
  }
}

// ---------------- persistent GRU scan: one kernel, grid barrier per step ----------------
// 64 blocks x 384 threads. Thread (q=tid/24, m=tid%24): W_hh[row(m)][32q..32q+32) in VGPRs.
// h staged in XOR-swizzled LDS; q-major tid => near-broadcast LDS reads.
__global__ __launch_bounds__(384) void k_gru_scan(
    const float* __restrict__ enc_h, const float* __restrict__ xg,
    const float* __restrict__ W_hh, const float* __restrict__ b_hh,
    float* __restrict__ gru_out, u32* __restrict__ bar) {
  __shared__ float hbuf[16 * 512];   // 32 KB, swizzled: granule g4 -> g4 ^ ((g4>>3)&7)
  __shared__ float pre[16 * 388];    // [q][u=m*16+b], padded stride
  __shared__ float gsum[384];
  __shared__ float bbias[24];
  int tid = threadIdx.x;
  int q = tid / 24, m = tid - q * 24;      // q in [0,16), m in [0,24)
  int gate = m >> 3, c = m & 7;
  int col0 = blockIdx.x * 8;
  int wrow = gate * 512 + col0 + c;
  float4 wv[8];
  const float4* wsrc = (const float4*)(W_hh + (size_t)wrow * 512 + q * 32);
#pragma unroll
  for (int jj = 0; jj < 8; ++jj) wv[jj] = wsrc[jj];
  if (tid < 24) bbias[tid] = b_hh[(tid >> 3) * 512 + col0 + (tid & 7)];

  for (int t = 0; t < T_; ++t) {
    const float* hsrc; size_t bstride;
    if (t == 0) { hsrc = enc_h; bstride = 512; }
    else { hsrc = gru_out + (size_t)(t - 1) * 512; bstride = (size_t)T_ * 512; }
    for (int i = tid; i < 2048; i += 384) {
      int b = i >> 7, g4 = i & 127;
      float4 v = *(const float4*)(hsrc + (size_t)b * bstride + g4 * 4);
      int pg = g4 ^ ((g4 >> 3) & 7);
      *(float4*)(&hbuf[b * 512 + pg * 4]) = v;
    }
    __syncthreads();
    // partial dots: thread covers k-slice [32q, 32q+32) for all 16 batches
    for (int b = 0; b < 16; ++b) {
      float4 fa = {0.f, 0.f, 0.f, 0.f};
#pragma unroll
      for (int jj = 0; jj < 8; ++jj) {
        int pg = (q * 8 + jj) ^ (q & 7);
        float4 hv = *(const float4*)(&hbuf[b * 512 + pg * 4]);
        fa.x = fmaf(wv[jj].x, hv.x, fa.x);
        fa.y = fmaf(wv[jj].y, hv.y, fa.y);
        fa.z = fmaf(wv[jj].z, hv.z, fa.z);
        fa.w = fmaf(wv[jj].w, hv.w, fa.w);
      }
      pre[q * 388 + m * 16 + b] = (fa.x + fa.y) + (fa.z + fa.w);
    }
    __syncthreads();
    {   // reduce over q: thread tid = u = m*16+b
      float S = 0.f;
#pragma unroll
      for (int qq = 0; qq < 16; ++qq) S += pre[qq * 388 + tid];
      gsum[tid] = S + bbias[tid >> 4];
    }
    __syncthreads();
    if (tid < 128) {
      int c2 = tid >> 4, b3 = tid & 15;
      int col = col0 + c2;
      const float* xgt = xg + (size_t)(b3 * T_ + t) * G_;
      float xr = xgt[col], xz = xgt[512 + col], xn = xgt[1024 + col];
      int gl = col >> 2, pg = gl ^ ((gl >> 3) & 7);
      float hp = hbuf[b3 * 512 + pg * 4 + (col & 3)];
      float r = 1.f / (1.f + expf(-(xr + gsum[c2 * 16 + b3])));
      float z = 1.f / (1.f + expf(-(xz + gsum[(8 + c2) * 16 + b3])));
      float n = tanhf(xn + r * gsum[(16 + c2) * 16 + b3]);
      gru_out[(size_t)(b3 * T_ + t) * 512 + col] = (1.f - z) * n + z * hp;
    }
    // ---- grid barrier (generation) ----
    __syncthreads();
    if (tid == 0) {
      __threadfence();
      u32 target = (u32)(t + 1);
      u32 arrived = __hip_atomic_fetch_add(&bar[0], 1u, __ATOMIC_ACQ_REL,
                                           __HIP_MEMORY_SCOPE_AGENT);
      if (arrived == NBLK_GRU - 1) {
        __hip_atomic_store(&bar[0], 0u, __ATOMIC_RELAXED, __HIP_MEMORY_SCOPE_AGENT);
        __hip_atomic_store(&bar[1], target, __ATOMIC_RELEASE, __HIP_MEMORY_SCOPE_AGENT);
      } else {
        while (__hip_atomic_load(&bar[1], __ATOMIC_ACQUIRE,
                                 __HIP_MEMORY_SCOPE_AGENT) < target)
          __builtin_amdgcn_s_sleep(2);
      }
    }
    __syncthreads();
  }
}

// ---------------- copy h_last ----------------
__global__ __launch_bounds__(256) void k_hlast(const float* __restrict__ gru_out,
                                               float* __restrict__ hlast) {
  int i = blockIdx.x * 256 + threadIdx.x;  // 8192
  int b = i >> 9, j = i & 511;
  hlast[i] = gru_out[((size_t)b * T_ + (T_ - 1)) * H_ + j];
}

// ---------------- attention: scores -> softmax -> mix -> combined ----------------
template <int WF32, int WBF>
__global__ __launch_bounds__(256) void k_attn(
    const float* __restrict__ gru_out, const float* __restrict__ enc,
    float* __restrict__ attn_out, float* __restrict__ combined,
    __bf16* __restrict__ comb_bf) {
  __shared__ float orow[H_];
  __shared__ float sc[S_];
  __shared__ float red[S_];
  int row = blockIdx.x;  // b*T + t
  int b = row >> 6;
  int tid = threadIdx.x;
  const float* o = gru_out + (size_t)row * H_;
  for (int i = tid; i < H_; i += 256) orow[i] = o[i];
  __syncthreads();
  if (tid < S_) {
    const float4* e4 = (const float4*)(enc + ((size_t)b * S_ + tid) * H_);
    const float4* o4 = (const float4*)orow;
    float acc = 0.f;
#pragma unroll 8
    for (int k = 0; k < H_ / 4; ++k) {
      float4 e = e4[k], x = o4[k];
      acc += e.x * x.x + e.y * x.y + e.z * x.z + e.w * x.w;
    }
    sc[tid] = acc; red[tid] = acc;
  }
  __syncthreads();
  for (int s = 64; s > 0; s >>= 1) {
    if (tid < s) red[tid] = fmaxf(red[tid], red[tid + s]);
    __syncthreads();
  }
  float mx = red[0];
  __syncthreads();
  if (tid < S_) { float p = expf(sc[tid] - mx); sc[tid] = p; red[tid] = p; }
  __syncthreads();
  for (int s = 64; s > 0; s >>= 1) {
    if (tid < s) red[tid] += red[tid + s];
    __syncthreads();
  }
  float inv = 1.f / red[0];
  __syncthreads();
  if (tid < S_) {
    float a = sc[tid] * inv;
    sc[tid] = a;
    attn_out[(size_t)row * S_ + tid] = a;
  }
  __syncthreads();
  float acc0 = 0.f, acc1 = 0.f;
  for (int s = 0; s < S_; ++s) {
    float a = sc[s];
    const float* e = enc + ((size_t)b * S_ + s) * H_;
    acc0 += a * e[tid];
    acc1 += a * e[tid + 256];
  }
  if (WF32) {
    float* crow = combined + (size_t)row * (2 * H_);
    crow[tid] = acc0; crow[256 + tid] = acc1;
    crow[512 + tid] = orow[tid]; crow[768 + tid] = orow[tid + 256];
  }
  if (WBF) {
    __bf16* cb = comb_bf + (size_t)row * (2 * H_);
    cb[tid] = (__bf16)acc0; cb[256 + tid] = (__bf16)acc1;
    cb[512 + tid] = (__bf16)orow[tid]; cb[768 + tid] = (__bf16)orow[tid + 256];
  }
}

// ---------------- in-place log_softmax over V per row ----------------
__global__ __launch_bounds__(1024) void k_logsoftmax(float* __restrict__ logits) {
  int row = blockIdx.x;
  float* x = logits + (size_t)row * V_;
  int tid = threadIdx.x;
  float m = -INFINITY, s = 0.f;
  for (int i = tid; i < V_; i += 1024) {
    float v = x[i];
    float mn = fmaxf(m, v);
    s = s * expf(m - mn) + expf(v - mn);
    m = mn;
  }
  __shared__ float sm[1024], ss[1024];
  sm[tid] = m; ss[tid] = s;
  __syncthreads();
  for (int st = 512; st > 0; st >>= 1) {
    if (tid < st) {
      float m2 = sm[tid + st], s2 = ss[tid + st];
      float mn = fmaxf(sm[tid], m2);
      ss[tid] = ss[tid] * expf(sm[tid] - mn) + s2 * expf(m2 - mn);
      sm[tid] = mn;
    }
    __syncthreads();
  }
  float L = logf(ss[0]) + sm[0];
  for (int i = tid; i < V_; i += 1024) x[i] = x[i] - L;
}

extern "C" void kernel_launch(void* const* d_in, const int* in_sizes, int n_in,
                              void* d_out, int out_size, void* d_ws, size_t ws_size,
                              hipStream_t stream) {
  const int*   inputs  = (const int*)d_in[0];
  const float* enc_h   = (const float*)d_in[1];
  const float* enc_out = (const float*)d_in[2];
  const float* emb     = (const float*)d_in[3];
  const float* W_ih    = (const float*)d_in[4];
  const float* W_hh    = (const float*)d_in[5];
  const float* b_ih    = (const float*)d_in[6];
  const float* b_hh    = (const float*)d_in[7];
  const float* attn_W  = (const float*)d_in[8];
  const float* attn_b  = (const float*)d_in[9];
  const float* out_W   = (const float*)d_in[10];
  const float* out_b   = (const float*)d_in[11];

  float* out       = (float*)d_out;
  float* log_probs = out;
  float* hlast     = out + (size_t)B_ * T_ * V_;
  float* attn      = hlast + B_ * H_;

  char* wsb = (char*)d_ws;
  // full-path layout (bytes)
  const size_t OFF_BAR   = 0;
  const size_t OFF_OUTWB = 256;
  const size_t OFF_XB    = OFF_OUTWB + (size_t)V_ * H_ * 2;        // 32,768,256
  const size_t OFF_XG    = OFF_XB + (size_t)1024 * H_ * 2;         // +1MB
  const size_t OFF_GRU   = OFF_XG + (size_t)1024 * G_ * 4;         // +6MB
  const size_t OFF_CB    = OFF_GRU + (size_t)1024 * H_ * 4;        // +2MB
  const size_t OFF_O2B   = OFF_CB + (size_t)1024 * 1024 * 2;       // +2MB
  const size_t OFF_WIHB  = OFF_O2B + (size_t)1024 * H_ * 2;        // +1MB
  const size_t OFF_AWB   = OFF_WIHB + (size_t)G_ * H_ * 2;         // +1.5MB
  const size_t NEED_FULL = OFF_AWB + (size_t)H_ * 1024 * 2;        // ~45.8MB

  if (ws_size >= NEED_FULL) {
    u32*     bar    = (u32*)(wsb + OFF_BAR);
    __bf16*  outWb  = (__bf16*)(wsb + OFF_OUTWB);
    __bf16*  Xb     = (__bf16*)(wsb + OFF_XB);
    float*   xg     = (float*)(wsb + OFF_XG);
    float*   gru    = (float*)(wsb + OFF_GRU);
    __bf16*  combb  = (__bf16*)(wsb + OFF_CB);
    __bf16*  out2b  = (__bf16*)(wsb + OFF_O2B);
    __bf16*  Wihb   = (__bf16*)(wsb + OFF_WIHB);
    __bf16*  aWb    = (__bf16*)(wsb + OFF_AWB);

    k_zero<<<1, 64, 0, stream>>>(bar);
    k_cast<<<2048, 256, 0, stream>>>(out_W, outWb, V_ * H_ / 4);
    k_cast<<<256, 256, 0, stream>>>(W_ih, Wihb, G_ * H_ / 4);
    k_cast<<<256, 256, 0, stream>>>(attn_W, aWb, H_ * 1024 / 4);
    k_gather_bf<<<1024, 128, 0, stream>>>(inputs, emb, Xb);
    // xg = X @ W_ih^T + b_ih   (M=1024, N=1536, K=512)
    k_gemm_bf16<0, 1, 0><<<96, 256, 0, stream>>>(Xb, Wihb, b_ih, xg, (__bf16*)0,
                                                 1024, G_, H_, 8, 0);
    k_gru_scan<<<NBLK_GRU, 384, 0, stream>>>(enc_h, xg, W_hh, b_hh, gru, bar);
    k_hlast<<<32, 256, 0, stream>>>(gru, hlast);
    k_attn<0, 1><<<1024, 256, 0, stream>>>(gru, enc_out, attn, (float*)0, combb);
    // out2 = tanh(combined @ attn_W^T + attn_b)  (M=1024, N=512, K=1024) -> bf16 only
    k_gemm_bf16<1, 0, 1><<<32, 256, 0, stream>>>(combb, aWb, attn_b, (float*)0,
                                                 out2b, 1024, H_, 1024, 8, 0);
    // logits = out2 @ out_W^T + out_b  (M=1024, N=32000, K=512), XCD-grouped grid
    k_gemm_bf16<0, 1, 0><<<2048, 256, 0, stream>>>(out2b, outWb, out_b, log_probs,
                                                   (__bf16*)0, 1024, V_, H_, 8, 1);
    k_logsoftmax<<<1024, 1024, 0, stream>>>(log_probs);
  } else {
    // legacy tier: round-2 layout (8MB) + persistent GRU (barrier in dead out2 region)
    float* ws       = (float*)d_ws;
    float* X        = ws;
    float* xg       = ws + 524288;
    float* gru      = ws;
    float* combined = ws + 524288;
    float* out2     = ws + 1572864;
    u32*   bar      = (u32*)(ws + 1572864);   // dead until attnproj

    k_zero<<<1, 64, 0, stream>>>(bar);
    k_gather32<<<1024, 128, 0, stream>>>(inputs, emb, X);
    k_gemm<0><<<dim3(8, 12), 256, 0, stream>>>(X, W_ih, b_ih, xg, 1024, G_, H_);
    k_gru_scan<<<NBLK_GRU, 384, 0, stream>>>(enc_h, xg, W_hh, b_hh, gru, bar);
    k_hlast<<<32, 256, 0, stream>>>(gru, hlast);
    k_attn<1, 0><<<1024, 256, 0, stream>>>(gru, enc_out, attn, combined, (__bf16*)0);
    k_gemm<1><<<dim3(8, 4), 256, 0, stream>>>(combined, attn_W, attn_b, out2,
                                              1024, H_, 2 * H_);
    k_gemm<0><<<dim3(8, 250), 256, 0, stream>>>(out2, out_W, out_b, log_probs,
                                                1024, V_, H_);
    k_logsoftmax<<<1024, 1024, 0, stream>>>(log_probs);
  }
}

// Round 6
// 1079.067 us; speedup vs baseline: 4.3357x; 1.0451x over previous
//
#include <hip/hip_runtime.h>
#include <math.h>

#define B_ 16
#define T1_ 65
#define T_ 64
#define S_ 128
#define H_ 512
#define G_ 1536   /* 3H */
#define V_ 32000
#define NBLK_GRU 64

typedef float f32x4 __attribute__((ext_vector_type(4)));
typedef __bf16 bf16x8 __attribute__((ext_vector_type(8)));
typedef __bf16 bf16x4 __attribute__((ext_vector_type(4)));
typedef short s16x4 __attribute__((ext_vector_type(4)));
typedef unsigned int u32;

__device__ __forceinline__ void gload16(const void* g, void* l) {
  __builtin_amdgcn_global_load_lds(
      (const __attribute__((address_space(1))) u32*)g,
      (__attribute__((address_space(3))) u32*)l, 16, 0, 0);
}

__device__ inline unsigned short f2bf(float f) {
  union { float f; unsigned u; } x; x.f = f;
  unsigned r = x.u + 0x7fff + ((x.u >> 16) & 1);  // RNE
  return (unsigned short)(r >> 16);
}

// ---------------- zero the barrier flags (4 KB: 64 flags x 64B stride) ----------------
__global__ void k_zero(u32* bar) { bar[threadIdx.x] = 0u; }   // <<<1,1024>>>

// ---------------- fp32 -> bf16 cast (n4 = n/4) ----------------
__global__ __launch_bounds__(256) void k_cast(const float* __restrict__ src,
                                              __bf16* __restrict__ dst, int n4) {
  int stride = gridDim.x * 256;
  for (int i = blockIdx.x * 256 + threadIdx.x; i < n4; i += stride) {
    float4 v = ((const float4*)src)[i];
    bf16x4 o = {(__bf16)v.x, (__bf16)v.y, (__bf16)v.z, (__bf16)v.w};
    ((bf16x4*)dst)[i] = o;
  }
}

// ---------------- gather X[row] = emb[tok] (bf16 out) ----------------
__global__ __launch_bounds__(128) void k_gather_bf(
    const int* __restrict__ inputs, const float* __restrict__ emb,
    __bf16* __restrict__ Xb) {
  int row = blockIdx.x;            // b*T + t
  int b = row >> 6, t = row & 63;
  int tok = inputs[b * T1_ + t];   // dec_in = inputs[:, :-1]
  float4 v = ((const float4*)(emb + (size_t)tok * H_))[threadIdx.x];
  bf16x4 o = {(__bf16)v.x, (__bf16)v.y, (__bf16)v.z, (__bf16)v.w};
  ((bf16x4*)(Xb + (size_t)row * H_))[threadIdx.x] = o;
}

// ---------------- gather X[row] = emb[tok] (fp32 out, legacy) ----------------
__global__ __launch_bounds__(128) void k_gather32(
    const int* __restrict__ inputs, const float* __restrict__ emb,
    float* __restrict__ X) {
  int row = blockIdx.x;
  int b = row >> 6, t = row & 63;
  int tok = inputs[b * T1_ + t];
  float4 v = ((const float4*)(emb + (size_t)tok * H_))[threadIdx.x];
  ((float4*)(X + (size_t)row * H_))[threadIdx.x] = v;
}

// ---------------- bf16 MFMA GEMM: C = act(A[M,K] @ W[N,K]^T + bias) ----------------
// global_load_lds(16B) staging, T2 XOR-swizzle via pre-swizzled global source.
// 128x128 tile, BK=64, 4 waves (2x2 of 64x64).
template <int TANH, int WF32, int WBF16>
__global__ __launch_bounds__(256) void k_gemm_bf16(
    const __bf16* __restrict__ A, const __bf16* __restrict__ W,
    const float* __restrict__ bias, float* __restrict__ C,
    __bf16* __restrict__ Cb, int M, int N, int K, int mb, int xcdmap) {
  __shared__ __align__(1024) char sA[16384];
  __shared__ __align__(1024) char sB[16384];
  int tid = threadIdx.x;
  int d = blockIdx.x, m_blk, n_blk;
  if (xcdmap) {
    int q = d >> 6, r = d & 63;
    m_blk = r >> 3; n_blk = q * 8 + (r & 7);
    if (n_blk * 128 >= N) return;
  } else {
    m_blk = d % mb; n_blk = d / mb;
  }
  int m0 = m_blk * 128, n0 = n_blk * 128;
  int lane = tid & 63, wave = tid >> 6;
  int wm = wave >> 1, wn = wave & 1;
  int lr = lane & 15, kg = lane >> 4;
  int lrow = lane >> 3, lcp = lane & 7;   // staging: row-in-chunk, phys col granule
  f32x4 acc[4][4] = {};

  for (int kk = 0; kk < K; kk += 64) {
    __syncthreads();
#pragma unroll
    for (int i = 0; i < 4; ++i) {
      int c = wave * 4 + i;             // 16 chunks of 1KB per tile
      int row = c * 8 + lrow;
      int cgl = lcp ^ (row & 7);        // pre-swizzled global source granule
      gload16(A + (size_t)(m0 + row) * K + kk + cgl * 8, sA + c * 1024 + lane * 16);
      gload16(W + (size_t)(n0 + row) * K + kk + cgl * 8, sB + c * 1024 + lane * 16);
    }
    __syncthreads();
#pragma unroll
    for (int ks = 0; ks < 2; ++ks) {
      bf16x8 af[4], bfr[4];
#pragma unroll
      for (int i = 0; i < 4; ++i) {
        int ra = wm * 64 + i * 16 + lr;
        af[i] = *(const bf16x8*)(sA + ra * 128 + ((ks * 64 + kg * 16) ^ ((ra & 7) << 4)));
        int rb = wn * 64 + i * 16 + lr;
        bfr[i] = *(const bf16x8*)(sB + rb * 128 + ((ks * 64 + kg * 16) ^ ((rb & 7) << 4)));
      }
#pragma unroll
      for (int mi = 0; mi < 4; ++mi)
#pragma unroll
        for (int ni = 0; ni < 4; ++ni)
          acc[mi][ni] = __builtin_amdgcn_mfma_f32_16x16x32_bf16(
              af[mi], bfr[ni], acc[mi][ni], 0, 0, 0);
    }
  }
  // epilogue: C/D layout col=lane&15, row=(lane>>4)*4+reg
#pragma unroll
  for (int ni = 0; ni < 4; ++ni) {
    int col = n0 + wn * 64 + ni * 16 + lr;
    float bv = bias[col];
#pragma unroll
    for (int mi = 0; mi < 4; ++mi) {
      int rbase = m0 + wm * 64 + mi * 16 + kg * 4;
#pragma unroll
      for (int j = 0; j < 4; ++j) {
        float v = acc[mi][ni][j] + bv;
        if (TANH) v = tanhf(v);
        if (WF32) C[(size_t)(rbase + j) * N + col] = v;
        if (WBF16) Cb[(size_t)(rbase + j) * N + col] = (__bf16)v;
      }
    }
  }
}

// ---------------- legacy fp32-staging MFMA GEMM (round-2) ----------------
template <int TANH>
__global__ __launch_bounds__(256) void k_gemm(
    const float* __restrict__ A, const float* __restrict__ W,
    const float* __restrict__ bias, float* __restrict__ C,
    int M, int N, int K) {
  __shared__ char sA[128 * 64 * 2];
  __shared__ char sB[128 * 64 * 2];
  int tid = threadIdx.x;
  int m0 = blockIdx.x * 128, n0 = blockIdx.y * 128;
  int lane = tid & 63, wave = tid >> 6;
  int wm = wave >> 1, wn = wave & 1;
  int lr = lane & 15, kg = lane >> 4;
  f32x4 acc[4][4] = {};
  for (int kk = 0; kk < K; kk += 64) {
    __syncthreads();
#pragma unroll
    for (int i = 0; i < 8; ++i) {
      int idx = tid + i * 256;
      int row = idx >> 4, kq = idx & 15;
      float4 va = *(const float4*)(A + (size_t)(m0 + row) * K + kk + kq * 4);
      float4 vb = *(const float4*)(W + (size_t)(n0 + row) * K + kk + kq * 4);
      int byte = (row * 128 + kq * 8) ^ ((row & 7) << 4);
      s16x4 pa; pa[0] = (short)f2bf(va.x); pa[1] = (short)f2bf(va.y);
      pa[2] = (short)f2bf(va.z); pa[3] = (short)f2bf(va.w);
      s16x4 pb; pb[0] = (short)f2bf(vb.x); pb[1] = (short)f2bf(vb.y);
      pb[2] = (short)f2bf(vb.z); pb[3] = (short)f2bf(vb.w);
      *(s16x4*)(sA + byte) = pa;
      *(s16x4*)(sB + byte) = pb;
    }
    __syncthreads();
#pragma unroll
    for (int ks = 0; ks < 2; ++ks) {
      bf16x8 af[4], bfr[4];
#pragma unroll
      for (int i = 0; i < 4; ++i) {
        int ra = wm * 64 + i * 16 + lr;
        af[i] = *(const bf16x8*)(sA + ((ra * 128 + ks * 64 + kg * 16) ^ ((ra & 7) << 4)));
        int rb = wn * 64 + i * 16 + lr;
        bfr[i] = *(const bf16x8*)(sB + ((rb * 128 + ks * 64 + kg * 16) ^ ((rb & 7) << 4)));
      }
#pragma unroll
      for (int mi = 0; mi < 4; ++mi)
#pragma unroll
        for (int ni = 0; ni < 4; ++ni)
          acc[mi][ni] = __builtin_amdgcn_mfma_f32_16x16x32_bf16(
              af[mi], bfr[ni], acc[mi][ni], 0, 0, 0);
    }
  }
#pragma unroll
  for (int ni = 0; ni < 4; ++ni) {
    int col = n0 + wn * 64 + ni * 16 + lr;
    float bv = bias[col];
#pragma unroll
    for (int mi = 0; mi < 4; ++mi) {
      int rbase = m0 + wm * 64 + mi * 16 + kg * 4;
#pragma unroll
      for (int j = 0; j < 4; ++j) {
        float v = acc[mi][ni][j] + bv;
        if (TANH) v = tanhf(v);
        C[(size_t)(rbase + j) * N + col] = v;
      }
    }
  }
}

// ---------------- persistent GRU scan: one kernel, flag-array grid barrier ----------------
// 64 blocks x 384 threads. Thread (q=tid/24, m=tid%24): W_hh[row(m)][32q..32q+32) in VGPRs.
// Barrier: block i release-stores generation into flags[i*16] (64B stride);
// wave 0 of EVERY block polls all 64 flags (one lane per flag) — no RMW contention.
__global__ __launch_bounds__(384) void k_gru_scan(
    const float* __restrict__ enc_h, const float* __restrict__ xg,
    const float* __restrict__ W_hh, const float* __restrict__ b_hh,
    float* __restrict__ gru_out, u32* __restrict__ flags) {
  __shared__ float hbuf[16 * 512];   // 32 KB, swizzled: granule g4 -> g4 ^ ((g4>>3)&7)
  __shared__ float pre[16 * 388];    // [q][u=m*16+b], padded stride
  __shared__ float gsum[384];
  __shared__ float bbias[24];
  int tid = threadIdx.x;
  int q = tid / 24, m = tid - q * 24;      // q in [0,16), m in [0,24)
  int gate = m >> 3, c = m & 7;
  int col0 = blockIdx.x * 8;
  int wrow = gate * 512 + col0 + c;
  float4 wv[8];
  const float4* wsrc = (const float4*)(W_hh + (size_t)wrow * 512 + q * 32);
#pragma unroll
  for (int jj = 0; jj < 8; ++jj) wv[jj] = wsrc[jj];
  if (tid < 24) bbias[tid] = b_hh[(tid >> 3) * 512 + col0 + (tid & 7)];

  for (int t = 0; t < T_; ++t) {
    // prefetch this step's xg (independent of h) — hides L3 latency under staging
    float xr = 0.f, xz = 0.f, xn = 0.f;
    if (tid < 128) {
      int c2 = tid >> 4, b3 = tid & 15;
      int col = col0 + c2;
      const float* xgt = xg + (size_t)(b3 * T_ + t) * G_;
      xr = xgt[col]; xz = xgt[512 + col]; xn = xgt[1024 + col];
    }
    const float* hsrc; size_t bstride;
    if (t == 0) { hsrc = enc_h; bstride = 512; }
    else { hsrc = gru_out + (size_t)(t - 1) * 512; bstride = (size_t)T_ * 512; }
    for (int i = tid; i < 2048; i += 384) {
      int b = i >> 7, g4 = i & 127;
      float4 v = *(const float4*)(hsrc + (size_t)b * bstride + g4 * 4);
      int pg = g4 ^ ((g4 >> 3) & 7);
      *(float4*)(&hbuf[b * 512 + pg * 4]) = v;
    }
    __syncthreads();
    // partial dots: thread covers k-slice [32q, 32q+32) for all 16 batches
    for (int b = 0; b < 16; ++b) {
      float4 fa = {0.f, 0.f, 0.f, 0.f};
#pragma unroll
      for (int jj = 0; jj < 8; ++jj) {
        int pg = (q * 8 + jj) ^ (q & 7);
        float4 hv = *(const float4*)(&hbuf[b * 512 + pg * 4]);
        fa.x = fmaf(wv[jj].x, hv.x, fa.x);
        fa.y = fmaf(wv[jj].y, hv.y, fa.y);
        fa.z = fmaf(wv[jj].z, hv.z, fa.z);
        fa.w = fmaf(wv[jj].w, hv.w, fa.w);
      }
      pre[q * 388 + m * 16 + b] = (fa.x + fa.y) + (fa.z + fa.w);
    }
    __syncthreads();
    {   // reduce over q: thread tid = u = m*16+b
      float S = 0.f;
#pragma unroll
      for (int qq = 0; qq < 16; ++qq) S += pre[qq * 388 + tid];
      gsum[tid] = S + bbias[tid >> 4];
    }
    __syncthreads();
    if (tid < 128) {
      int c2 = tid >> 4, b3 = tid & 15;
      int col = col0 + c2;
      int gl = col >> 2, pg = gl ^ ((gl >> 3) & 7);
      float hp = hbuf[b3 * 512 + pg * 4 + (col & 3)];
      float r = 1.f / (1.f + expf(-(xr + gsum[c2 * 16 + b3])));
      float z = 1.f / (1.f + expf(-(xz + gsum[(8 + c2) * 16 + b3])));
      float n = tanhf(xn + r * gsum[(16 + c2) * 16 + b3]);
      gru_out[(size_t)(b3 * T_ + t) * 512 + col] = (1.f - z) * n + z * hp;
      __threadfence();   // flush own h-stores (waves 0-1 uniform)
    }
    __syncthreads();
    if (t < T_ - 1) {     // final step synchronized by kernel boundary
      if (tid == 0)
        __hip_atomic_store(&flags[(u32)blockIdx.x * 16], (u32)(t + 1),
                           __ATOMIC_RELEASE, __HIP_MEMORY_SCOPE_AGENT);
      if (tid < 64) {
        u32 target = (u32)(t + 1);
        while (1) {
          u32 v = __hip_atomic_load(&flags[tid * 16], __ATOMIC_ACQUIRE,
                                    __HIP_MEMORY_SCOPE_AGENT);
          if (__all((int)(v >= target))) break;
          __builtin_amdgcn_s_sleep(1);
        }
      }
      __syncthreads();
    }
  }
}

// ---------------- copy h_last ----------------
__global__ __launch_bounds__(256) void k_hlast(const float* __restrict__ gru_out,
                                               float* __restrict__ hlast) {
  int i = blockIdx.x * 256 + threadIdx.x;  // 8192
  int b = i >> 9, j = i & 511;
  hlast[i] = gru_out[((size_t)b * T_ + (T_ - 1)) * H_ + j];
}

// ---------------- attention: scores -> softmax -> mix -> combined ----------------
template <int WF32, int WBF>
__global__ __launch_bounds__(256) void k_attn(
    const float* __restrict__ gru_out, const float* __restrict__ enc,
    float* __restrict__ attn_out, float* __restrict__ combined,
    __bf16* __restrict__ comb_bf) {
  __shared__ float orow[H_];
  __shared__ float sc[S_];
  __shared__ float red[S_];
  int row = blockIdx.x;  // b*T + t
  int b = row >> 6;
  int tid = threadIdx.x;
  const float* o = gru_out + (size_t)row * H_;
  for (int i = tid; i < H_; i += 256) orow[i] = o[i];
  __syncthreads();
  if (tid < S_) {
    const float4* e4 = (const float4*)(enc + ((size_t)b * S_ + tid) * H_);
    const float4* o4 = (const float4*)orow;
    float acc = 0.f;
#pragma unroll 8
    for (int k = 0; k < H_ / 4; ++k) {
      float4 e = e4[k], x = o4[k];
      acc += e.x * x.x + e.y * x.y + e.z * x.z + e.w * x.w;
    }
    sc[tid] = acc; red[tid] = acc;
  }
  __syncthreads();
  for (int s = 64; s > 0; s >>= 1) {
    if (tid < s) red[tid] = fmaxf(red[tid], red[tid + s]);
    __syncthreads();
  }
  float mx = red[0];
  __syncthreads();
  if (tid < S_) { float p = expf(sc[tid] - mx); sc[tid] = p; red[tid] = p; }
  __syncthreads();
  for (int s = 64; s > 0; s >>= 1) {
    if (tid < s) red[tid] += red[tid + s];
    __syncthreads();
  }
  float inv = 1.f / red[0];
  __syncthreads();
  if (tid < S_) {
    float a = sc[tid] * inv;
    sc[tid] = a;
    attn_out[(size_t)row * S_ + tid] = a;
  }
  __syncthreads();
  float acc0 = 0.f, acc1 = 0.f;
  for (int s = 0; s < S_; ++s) {
    float a = sc[s];
    const float* e = enc + ((size_t)b * S_ + s) * H_;
    acc0 += a * e[tid];
    acc1 += a * e[tid + 256];
  }
  if (WF32) {
    float* crow = combined + (size_t)row * (2 * H_);
    crow[tid] = acc0; crow[256 + tid] = acc1;
    crow[512 + tid] = orow[tid]; crow[768 + tid] = orow[tid + 256];
  }
  if (WBF) {
    __bf16* cb = comb_bf + (size_t)row * (2 * H_);
    cb[tid] = (__bf16)acc0; cb[256 + tid] = (__bf16)acc1;
    cb[512 + tid] = (__bf16)orow[tid]; cb[768 + tid] = (__bf16)orow[tid + 256];
  }
}

// ---------------- in-place log_softmax over V per row ----------------
__global__ __launch_bounds__(1024) void k_logsoftmax(float* __restrict__ logits) {
  int row = blockIdx.x;
  float* x = logits + (size_t)row * V_;
  int tid = threadIdx.x;
  float m = -INFINITY, s = 0.f;
  for (int i = tid; i < V_; i += 1024) {
    float v = x[i];
    float mn = fmaxf(m, v);
    s = s * expf(m - mn) + expf(v - mn);
    m = mn;
  }
  __shared__ float sm[1024], ss[1024];
  sm[tid] = m; ss[tid] = s;
  __syncthreads();
  for (int st = 512; st > 0; st >>= 1) {
    if (tid < st) {
      float m2 = sm[tid + st], s2 = ss[tid + st];
      float mn = fmaxf(sm[tid], m2);
      ss[tid] = ss[tid] * expf(sm[tid] - mn) + s2 * expf(m2 - mn);
      sm[tid] = mn;
    }
    __syncthreads();
  }
  float L = logf(ss[0]) + sm[0];
  for (int i = tid; i < V_; i += 1024) x[i] = x[i] - L;
}

extern "C" void kernel_launch(void* const* d_in, const int* in_sizes, int n_in,
                              void* d_out, int out_size, void* d_ws, size_t ws_size,
                              hipStream_t stream) {
  const int*   inputs  = (const int*)d_in[0];
  const float* enc_h   = (const float*)d_in[1];
  const float* enc_out = (const float*)d_in[2];
  const float* emb     = (const float*)d_in[3];
  const float* W_ih    = (const float*)d_in[4];
  const float* W_hh    = (const float*)d_in[5];
  const float* b_ih    = (const float*)d_in[6];
  const float* b_hh    = (const float*)d_in[7];
  const float* attn_W  = (const float*)d_in[8];
  const float* attn_b  = (const float*)d_in[9];
  const float* out_W   = (const float*)d_in[10];
  const float* out_b   = (const float*)d_in[11];

  float* out       = (float*)d_out;
  float* log_probs = out;
  float* hlast     = out + (size_t)B_ * T_ * V_;
  float* attn      = hlast + B_ * H_;

  char* wsb = (char*)d_ws;
  // full-path layout (bytes)
  const size_t OFF_BAR   = 0;                                      // 4 KB flags
  const size_t OFF_OUTWB = 4096;
  const size_t OFF_XB    = OFF_OUTWB + (size_t)V_ * H_ * 2;
  const size_t OFF_XG    = OFF_XB + (size_t)1024 * H_ * 2;
  const size_t OFF_GRU   = OFF_XG + (size_t)1024 * G_ * 4;
  const size_t OFF_CB    = OFF_GRU + (size_t)1024 * H_ * 4;
  const size_t OFF_O2B   = OFF_CB + (size_t)1024 * 1024 * 2;
  const size_t OFF_WIHB  = OFF_O2B + (size_t)1024 * H_ * 2;
  const size_t OFF_AWB   = OFF_WIHB + (size_t)G_ * H_ * 2;
  const size_t NEED_FULL = OFF_AWB + (size_t)H_ * 1024 * 2;        // ~45.8MB

  if (ws_size >= NEED_FULL) {
    u32*     bar    = (u32*)(wsb + OFF_BAR);
    __bf16*  outWb  = (__bf16*)(wsb + OFF_OUTWB);
    __bf16*  Xb     = (__bf16*)(wsb + OFF_XB);
    float*   xg     = (float*)(wsb + OFF_XG);
    float*   gru    = (float*)(wsb + OFF_GRU);
    __bf16*  combb  = (__bf16*)(wsb + OFF_CB);
    __bf16*  out2b  = (__bf16*)(wsb + OFF_O2B);
    __bf16*  Wihb   = (__bf16*)(wsb + OFF_WIHB);
    __bf16*  aWb    = (__bf16*)(wsb + OFF_AWB);

    k_zero<<<1, 1024, 0, stream>>>(bar);
    k_cast<<<2048, 256, 0, stream>>>(out_W, outWb, V_ * H_ / 4);
    k_cast<<<256, 256, 0, stream>>>(W_ih, Wihb, G_ * H_ / 4);
    k_cast<<<256, 256, 0, stream>>>(attn_W, aWb, H_ * 1024 / 4);
    k_gather_bf<<<1024, 128, 0, stream>>>(inputs, emb, Xb);
    // xg = X @ W_ih^T + b_ih   (M=1024, N=1536, K=512)
    k_gemm_bf16<0, 1, 0><<<96, 256, 0, stream>>>(Xb, Wihb, b_ih, xg, (__bf16*)0,
                                                 1024, G_, H_, 8, 0);
    k_gru_scan<<<NBLK_GRU, 384, 0, stream>>>(enc_h, xg, W_hh, b_hh, gru, bar);
    k_hlast<<<32, 256, 0, stream>>>(gru, hlast);
    k_attn<0, 1><<<1024, 256, 0, stream>>>(gru, enc_out, attn, (float*)0, combb);
    // out2 = tanh(combined @ attn_W^T + attn_b)  (M=1024, N=512, K=1024) -> bf16 only
    k_gemm_bf16<1, 0, 1><<<32, 256, 0, stream>>>(combb, aWb, attn_b, (float*)0,
                                                 out2b, 1024, H_, 1024, 8, 0);
    // logits = out2 @ out_W^T + out_b  (M=1024, N=32000, K=512), XCD-grouped grid
    k_gemm_bf16<0, 1, 0><<<2048, 256, 0, stream>>>(out2b, outWb, out_b, log_probs,
                                                   (__bf16*)0, 1024, V_, H_, 8, 1);
    k_logsoftmax<<<1024, 1024, 0, stream>>>(log_probs);
  } else {
    // legacy tier: round-2 layout (8MB) + persistent GRU (flags in dead out2 region)
    float* ws       = (float*)d_ws;
    float* X        = ws;
    float* xg       = ws + 524288;
    float* gru      = ws;
    float* combined = ws + 524288;
    float* out2     = ws + 1572864;
    u32*   bar      = (u32*)(ws + 1572864);   // dead until attnproj

    k_zero<<<1, 1024, 0, stream>>>(bar);
    k_gather32<<<1024, 128, 0, stream>>>(inputs, emb, X);
    k_gemm<0><<<dim3(8, 12), 256, 0, stream>>>(X, W_ih, b_ih, xg, 1024, G_, H_);
    k_gru_scan<<<NBLK_GRU, 384, 0, stream>>>(enc_h, xg, W_hh, b_hh, gru, bar);
    k_hlast<<<32, 256, 0, stream>>>(gru, hlast);
    k_attn<1, 0><<<1024, 256, 0, stream>>>(gru, enc_out, attn, combined, (__bf16*)0);
    k_gemm<1><<<dim3(8, 4), 256, 0, stream>>>(combined, attn_W, attn_b, out2,
                                              1024, H_, 2 * H_);
    k_gemm<0><<<dim3(8, 250), 256, 0, stream>>>(out2, out_W, out_b, log_probs,
                                                1024, V_, H_);
    k_logsoftmax<<<1024, 1024, 0, stream>>>(log_probs);
  }
}

// Round 9
// 749.162 us; speedup vs baseline: 6.2450x; 1.4404x over previous
//
#include <hip/hip_runtime.h>
#include <math.h>

#define B_ 16
#define T1_ 65
#define T_ 64
#define S_ 128
#define H_ 512
#define G_ 1536   /* 3H */
#define V_ 32000
#define NBLK_GRU 64

typedef float f32x4 __attribute__((ext_vector_type(4)));
typedef __bf16 bf16x8 __attribute__((ext_vector_type(8)));
typedef __bf16 bf16x4 __attribute__((ext_vector_type(4)));
typedef short s16x4 __attribute__((ext_vector_type(4)));
typedef unsigned int u32;

__device__ __forceinline__ void gload16(const void* g, void* l) {
  __builtin_amdgcn_global_load_lds(
      (const __attribute__((address_space(1))) u32*)g,
      (__attribute__((address_space(3))) u32*)l, 16, 0, 0);
}

__device__ inline unsigned short f2bf(float f) {
  union { float f; unsigned u; } x; x.f = f;
  unsigned r = x.u + 0x7fff + ((x.u >> 16) & 1);  // RNE
  return (unsigned short)(r >> 16);
}

// ---- sc0 sc1 (coherence-point) memory ops: bypass L1/L2, no wbl2/inv needed ----
__device__ __forceinline__ float4 ld_sc_f4(const float* p) {
  float4 r;
  asm volatile("global_load_dwordx4 %0, %1, off sc0 sc1"
               : "=&v"(r) : "v"(p) : "memory");
  return r;
}
__device__ __forceinline__ void st_sc_f(float* p, float v) {
  asm volatile("global_store_dword %0, %1, off sc0 sc1" :: "v"(p), "v"(v) : "memory");
}
__device__ __forceinline__ u32 ld_sc_u32(const u32* p) {
  u32 r;
  asm volatile("global_load_dword %0, %1, off sc0 sc1\n\ts_waitcnt vmcnt(0)"
               : "=v"(r) : "v"(p) : "memory");
  return r;
}
__device__ __forceinline__ void st_sc_u32(u32* p, u32 v) {
  asm volatile("global_store_dword %0, %1, off sc0 sc1" :: "v"(p), "v"(v) : "memory");
}
__device__ __forceinline__ void wait_vm0() {
  asm volatile("s_waitcnt vmcnt(0)" ::: "memory");
}

// ---------------- zero the barrier flags (4 KB: 64 flags x 64B stride) ----------------
__global__ void k_zero(u32* bar) { bar[threadIdx.x] = 0u; }   // <<<1,1024>>>

// ---------------- fp32 -> bf16 cast (n4 = n/4) ----------------
__global__ __launch_bounds__(256) void k_cast(const float* __restrict__ src,
                                              __bf16* __restrict__ dst, int n4) {
  int stride = gridDim.x * 256;
  for (int i = blockIdx.x * 256 + threadIdx.x; i < n4; i += stride) {
    float4 v = ((const float4*)src)[i];
    bf16x4 o = {(__bf16)v.x, (__bf16)v.y, (__bf16)v.z, (__bf16)v.w};
    ((bf16x4*)dst)[i] = o;
  }
}

// ---------------- gather X[row] = emb[tok] (bf16 out) ----------------
__global__ __launch_bounds__(128) void k_gather_bf(
    const int* __restrict__ inputs, const float* __restrict__ emb,
    __bf16* __restrict__ Xb) {
  int row = blockIdx.x;            // b*T + t
  int b = row >> 6, t = row & 63;
  int tok = inputs[b * T1_ + t];   // dec_in = inputs[:, :-1]
  float4 v = ((const float4*)(emb + (size_t)tok * H_))[threadIdx.x];
  bf16x4 o = {(__bf16)v.x, (__bf16)v.y, (__bf16)v.z, (__bf16)v.w};
  ((bf16x4*)(Xb + (size_t)row * H_))[threadIdx.x] = o;
}

// ---------------- gather X[row] = emb[tok] (fp32 out, legacy) ----------------
__global__ __launch_bounds__(128) void k_gather32(
    const int* __restrict__ inputs, const float* __restrict__ emb,
    float* __restrict__ X) {
  int row = blockIdx.x;
  int b = row >> 6, t = row & 63;
  int tok = inputs[b * T1_ + t];
  float4 v = ((const float4*)(emb + (size_t)tok * H_))[threadIdx.x];
  ((float4*)(X + (size_t)row * H_))[threadIdx.x] = v;
}

// ---------------- bf16 MFMA GEMM: C = act(A[M,K] @ W[N,K]^T + bias) ----------------
// global_load_lds(16B) staging, T2 XOR-swizzle via pre-swizzled global source.
// 128x128 tile, BK=64, 4 waves (2x2 of 64x64).
template <int TANH, int WF32, int WBF16>
__global__ __launch_bounds__(256) void k_gemm_bf16(
    const __bf16* __restrict__ A, const __bf16* __restrict__ W,
    const float* __restrict__ bias, float* __restrict__ C,
    __bf16* __restrict__ Cb, int M, int N, int K, int mb, int xcdmap) {
  __shared__ __align__(1024) char sA[16384];
  __shared__ __align__(1024) char sB[16384];
  int tid = threadIdx.x;
  int d = blockIdx.x, m_blk, n_blk;
  if (xcdmap) {
    int q = d >> 6, r = d & 63;
    m_blk = r >> 3; n_blk = q * 8 + (r & 7);
    if (n_blk * 128 >= N) return;
  } else {
    m_blk = d % mb; n_blk = d / mb;
  }
  int m0 = m_blk * 128, n0 = n_blk * 128;
  int lane = tid & 63, wave = tid >> 6;
  int wm = wave >> 1, wn = wave & 1;
  int lr = lane & 15, kg = lane >> 4;
  int lrow = lane >> 3, lcp = lane & 7;   // staging: row-in-chunk, phys col granule
  f32x4 acc[4][4] = {};

  for (int kk = 0; kk < K; kk += 64) {
    __syncthreads();
#pragma unroll
    for (int i = 0; i < 4; ++i) {
      int c = wave * 4 + i;             // 16 chunks of 1KB per tile
      int row = c * 8 + lrow;
      int cgl = lcp ^ (row & 7);        // pre-swizzled global source granule
      gload16(A + (size_t)(m0 + row) * K + kk + cgl * 8, sA + c * 1024 + lane * 16);
      gload16(W + (size_t)(n0 + row) * K + kk + cgl * 8, sB + c * 1024 + lane * 16);
    }
    __syncthreads();
#pragma unroll
    for (int ks = 0; ks < 2; ++ks) {
      bf16x8 af[4], bfr[4];
#pragma unroll
      for (int i = 0; i < 4; ++i) {
        int ra = wm * 64 + i * 16 + lr;
        af[i] = *(const bf16x8*)(sA + ra * 128 + ((ks * 64 + kg * 16) ^ ((ra & 7) << 4)));
        int rb = wn * 64 + i * 16 + lr;
        bfr[i] = *(const bf16x8*)(sB + rb * 128 + ((ks * 64 + kg * 16) ^ ((rb & 7) << 4)));
      }
#pragma unroll
      for (int mi = 0; mi < 4; ++mi)
#pragma unroll
        for (int ni = 0; ni < 4; ++ni)
          acc[mi][ni] = __builtin_amdgcn_mfma_f32_16x16x32_bf16(
              af[mi], bfr[ni], acc[mi][ni], 0, 0, 0);
    }
  }
  // epilogue: C/D layout col=lane&15, row=(lane>>4)*4+reg
#pragma unroll
  for (int ni = 0; ni < 4; ++ni) {
    int col = n0 + wn * 64 + ni * 16 + lr;
    float bv = bias[col];
#pragma unroll
    for (int mi = 0; mi < 4; ++mi) {
      int rbase = m0 + wm * 64 + mi * 16 + kg * 4;
#pragma unroll
      for (int j = 0; j < 4; ++j) {
        float v = acc[mi][ni][j] + bv;
        if (TANH) v = tanhf(v);
        if (WF32) C[(size_t)(rbase + j) * N + col] = v;
        if (WBF16) Cb[(size_t)(rbase + j) * N + col] = (__bf16)v;
      }
    }
  }
}

// ---------------- legacy fp32-staging MFMA GEMM (round-2) ----------------
template <int TANH>
__global__ __launch_bounds__(256) void k_gemm(
    const float* __restrict__ A, const float* __restrict__ W,
    const float* __restrict__ bias, float* __restrict__ C,
    int M, int N, int K) {
  __shared__ char sA[128 * 64 * 2];
  __shared__ char sB[128 * 64 * 2];
  int tid = threadIdx.x;
  int m0 = blockIdx.x * 128, n0 = blockIdx.y * 128;
  int lane = tid & 63, wave = tid >> 6;
  int wm = wave >> 1, wn = wave & 1;
  int lr = lane & 15, kg = lane >> 4;
  f32x4 acc[4][4] = {};
  for (int kk = 0; kk < K; kk += 64) {
    __syncthreads();
#pragma unroll
    for (int i = 0; i < 8; ++i) {
      int idx = tid + i * 256;
      int row = idx >> 4, kq = idx & 15;
      float4 va = *(const float4*)(A + (size_t)(m0 + row) * K + kk + kq * 4);
      float4 vb = *(const float4*)(W + (size_t)(n0 + row) * K + kk + kq * 4);
      int byte = (row * 128 + kq * 8) ^ ((row & 7) << 4);
      s16x4 pa; pa[0] = (short)f2bf(va.x); pa[1] = (short)f2bf(va.y);
      pa[2] = (short)f2bf(va.z); pa[3] = (short)f2bf(va.w);
      s16x4 pb; pb[0] = (short)f2bf(vb.x); pb[1] = (short)f2bf(vb.y);
      pb[2] = (short)f2bf(vb.z); pb[3] = (short)f2bf(vb.w);
      *(s16x4*)(sA + byte) = pa;
      *(s16x4*)(sB + byte) = pb;
    }
    __syncthreads();
#pragma unroll
    for (int ks = 0; ks < 2; ++ks) {
      bf16x8 af[4], bfr[4];
#pragma unroll
      for (int i = 0; i < 4; ++i) {
        int ra = wm * 64 + i * 16 + lr;
        af[i] = *(const bf16x8*)(sA + ((ra * 128 + ks * 64 + kg * 16) ^ ((ra & 7) << 4)));
        int rb = wn * 64 + i * 16 + lr;
        bfr[i] = *(const bf16x8*)(sB + ((rb * 128 + ks * 64 + kg * 16) ^ ((rb & 7) << 4)));
      }
#pragma unroll
      for (int mi = 0; mi < 4; ++mi)
#pragma unroll
        for (int ni = 0; ni < 4; ++ni)
          acc[mi][ni] = __builtin_amdgcn_mfma_f32_16x16x32_bf16(
              af[mi], bfr[ni], acc[mi][ni], 0, 0, 0);
    }
  }
#pragma unroll
  for (int ni = 0; ni < 4; ++ni) {
    int col = n0 + wn * 64 + ni * 16 + lr;
    float bv = bias[col];
#pragma unroll
    for (int mi = 0; mi < 4; ++mi) {
      int rbase = m0 + wm * 64 + mi * 16 + kg * 4;
#pragma unroll
      for (int j = 0; j < 4; ++j) {
        float v = acc[mi][ni][j] + bv;
        if (TANH) v = tanhf(v);
        C[(size_t)(rbase + j) * N + col] = v;
      }
    }
  }
}

// ---------------- persistent GRU scan: sc0sc1 (MALL-coherent) exchange ----------------
// 64 blocks x 384 threads. Thread (q=tid/24, m=tid%24): W_hh[row(m)][32q..32q+32) in VGPRs.
// No threadfence / no acquire: all cross-block data moves via sc0 sc1 ops that
// bypass L1/L2 and meet at the coherence point. Producer: h stores (sc) ->
// per-wave vmcnt(0) -> flag store (sc). Consumers: 64-lane sc poll -> sc loads.
__global__ __launch_bounds__(384) void k_gru_scan(
    const float* __restrict__ enc_h, const float* __restrict__ xg,
    const float* __restrict__ W_hh, const float* __restrict__ b_hh,
    float* __restrict__ gru_out, u32* __restrict__ flags) {
  __shared__ float hbuf[16 * 512];   // 32 KB, swizzled: granule g4 -> g4 ^ ((g4>>3)&7)
  __shared__ float pre[16 * 392];    // [q][b*24+m] padded stride -> stride-1 reduce
  __shared__ float gsum[384];        // [b*24 + gate*8 + c]
  __shared__ float bbias[24];
  int tid = threadIdx.x;
  int q = tid / 24, m = tid - q * 24;      // q in [0,16), m in [0,24)
  int gate = m >> 3, c = m & 7;
  int rb = tid / 24, rm = tid - rb * 24;   // reduce-phase mapping tid = b*24+m
  int col0 = blockIdx.x * 8;
  int wrow = gate * 512 + col0 + c;
  float4 wv[8];
  const float4* wsrc = (const float4*)(W_hh + (size_t)wrow * 512 + q * 32);
#pragma unroll
  for (int jj = 0; jj < 8; ++jj) wv[jj] = wsrc[jj];
  if (tid < 24) bbias[tid] = b_hh[(tid >> 3) * 512 + col0 + (tid & 7)];

  for (int t = 0; t < T_; ++t) {
    // prefetch this step's xg (independent of h; plain cached loads)
    float xr = 0.f, xz = 0.f, xn = 0.f;
    if (tid < 128) {
      int c2 = tid >> 4, b3 = tid & 15;
      int col = col0 + c2;
      const float* xgt = xg + (size_t)(b3 * T_ + t) * G_;
      xr = xgt[col]; xz = xgt[512 + col]; xn = xgt[1024 + col];
    }
    const float* hsrc; size_t bstride;
    if (t == 0) { hsrc = enc_h; bstride = 512; }
    else { hsrc = gru_out + (size_t)(t - 1) * 512; bstride = (size_t)T_ * 512; }
    // ---- stage h: 5 full rounds + 1 partial, sc loads issued back-to-back ----
    float4 rr[6];
#pragma unroll
    for (int k = 0; k < 5; ++k) {
      int i = tid + k * 384;
      int b = i >> 7, g4 = i & 127;
      rr[k] = ld_sc_f4(hsrc + (size_t)b * bstride + g4 * 4);
    }
    {
      int i5 = tid + 1920; int i5c = i5 < 2048 ? i5 : 2047;
      rr[5] = ld_sc_f4(hsrc + (size_t)(i5c >> 7) * bstride + (i5c & 127) * 4);
    }
    wait_vm0();
#pragma unroll
    for (int k = 0; k < 6; ++k) {
      int i = tid + k * 384;
      if (i < 2048) {
        int b = i >> 7, g4 = i & 127;
        int pg = g4 ^ ((g4 >> 3) & 7);
        *(float4*)(&hbuf[b * 512 + pg * 4]) = rr[k];
      }
    }
    __syncthreads();
    // partial dots: thread covers k-slice [32q, 32q+32) for all 16 batches
    for (int b = 0; b < 16; ++b) {
      float4 fa = {0.f, 0.f, 0.f, 0.f};
#pragma unroll
      for (int jj = 0; jj < 8; ++jj) {
        int pg = (q * 8 + jj) ^ (q & 7);
        float4 hv = *(const float4*)(&hbuf[b * 512 + pg * 4]);
        fa.x = fmaf(wv[jj].x, hv.x, fa.x);
        fa.y = fmaf(wv[jj].y, hv.y, fa.y);
        fa.z = fmaf(wv[jj].z, hv.z, fa.z);
        fa.w = fmaf(wv[jj].w, hv.w, fa.w);
      }
      pre[q * 392 + b * 24 + m] = (fa.x + fa.y) + (fa.z + fa.w);
    }
    __syncthreads();
    {   // reduce over q: thread tid = b*24+m, stride-1 (conflict-free)
      float S = 0.f;
#pragma unroll
      for (int qq = 0; qq < 16; ++qq) S += pre[qq * 392 + tid];
      gsum[tid] = S + bbias[rm];
    }
    __syncthreads();
    if (tid < 128) {
      int c2 = tid >> 4, b3 = tid & 15;
      int col = col0 + c2;
      int gl = col >> 2, pg = gl ^ ((gl >> 3) & 7);
      float hp = hbuf[b3 * 512 + pg * 4 + (col & 3)];
      float r = 1.f / (1.f + expf(-(xr + gsum[b3 * 24 + c2])));
      float z = 1.f / (1.f + expf(-(xz + gsum[b3 * 24 + 8 + c2])));
      float n = tanhf(xn + r * gsum[b3 * 24 + 16 + c2]);
      st_sc_f(gru_out + (size_t)(b3 * T_ + t) * 512 + col, (1.f - z) * n + z * hp);
      wait_vm0();   // per-wave drain: stores at coherence point before barrier
    }
    __syncthreads();
    if (t < T_ - 1) {     // final step synchronized by kernel boundary
      if (tid == 0) st_sc_u32(&flags[(u32)blockIdx.x * 16], (u32)(t + 1));
      if (tid < 64) {
        u32 target = (u32)(t + 1);
        while (1) {
          u32 v = ld_sc_u32(&flags[tid * 16]);
          if (__all((int)(v >= target))) break;
        }
      }
      __syncthreads();
    }
  }
}

// ---------------- copy h_last ----------------
__global__ __launch_bounds__(256) void k_hlast(const float* __restrict__ gru_out,
                                               float* __restrict__ hlast) {
  int i = blockIdx.x * 256 + threadIdx.x;  // 8192
  int b = i >> 9, j = i & 511;
  hlast[i] = gru_out[((size_t)b * T_ + (T_ - 1)) * H_ + j];
}

// ---------------- attention: scores -> softmax -> mix -> combined ----------------
template <int WF32, int WBF>
__global__ __launch_bounds__(256) void k_attn(
    const float* __restrict__ gru_out, const float* __restrict__ enc,
    float* __restrict__ attn_out, float* __restrict__ combined,
    __bf16* __restrict__ comb_bf) {
  __shared__ float orow[H_];
  __shared__ float sc[S_];
  __shared__ float red[S_];
  int row = blockIdx.x;  // b*T + t
  int b = row >> 6;
  int tid = threadIdx.x;
  const float* o = gru_out + (size_t)row * H_;
  for (int i = tid; i < H_; i += 256) orow[i] = o[i];
  __syncthreads();
  if (tid < S_) {
    const float4* e4 = (const float4*)(enc + ((size_t)b * S_ + tid) * H_);
    const float4* o4 = (const float4*)orow;
    float acc = 0.f;
#pragma unroll 8
    for (int k = 0; k < H_ / 4; ++k) {
      float4 e = e4[k], x = o4[k];
      acc += e.x * x.x + e.y * x.y + e.z * x.z + e.w * x.w;
    }
    sc[tid] = acc; red[tid] = acc;
  }
  __syncthreads();
  for (int s = 64; s > 0; s >>= 1) {
    if (tid < s) red[tid] = fmaxf(red[tid], red[tid + s]);
    __syncthreads();
  }
  float mx = red[0];
  __syncthreads();
  if (tid < S_) { float p = expf(sc[tid] - mx); sc[tid] = p; red[tid] = p; }
  __syncthreads();
  for (int s = 64; s > 0; s >>= 1) {
    if (tid < s) red[tid] += red[tid + s];
    __syncthreads();
  }
  float inv = 1.f / red[0];
  __syncthreads();
  if (tid < S_) {
    float a = sc[tid] * inv;
    sc[tid] = a;
    attn_out[(size_t)row * S_ + tid] = a;
  }
  __syncthreads();
  float acc0 = 0.f, acc1 = 0.f;
  for (int s = 0; s < S_; ++s) {
    float a = sc[s];
    const float* e = enc + ((size_t)b * S_ + s) * H_;
    acc0 += a * e[tid];
    acc1 += a * e[tid + 256];
  }
  if (WF32) {
    float* crow = combined + (size_t)row * (2 * H_);
    crow[tid] = acc0; crow[256 + tid] = acc1;
    crow[512 + tid] = orow[tid]; crow[768 + tid] = orow[tid + 256];
  }
  if (WBF) {
    __bf16* cb = comb_bf + (size_t)row * (2 * H_);
    cb[tid] = (__bf16)acc0; cb[256 + tid] = (__bf16)acc1;
    cb[512 + tid] = (__bf16)orow[tid]; cb[768 + tid] = (__bf16)orow[tid + 256];
  }
}

// ---------------- in-place log_softmax over V per row ----------------
__global__ __launch_bounds__(1024) void k_logsoftmax(float* __restrict__ logits) {
  int row = blockIdx.x;
  float* x = logits + (size_t)row * V_;
  int tid = threadIdx.x;
  float m = -INFINITY, s = 0.f;
  for (int i = tid; i < V_; i += 1024) {
    float v = x[i];
    float mn = fmaxf(m, v);
    s = s * expf(m - mn) + expf(v - mn);
    m = mn;
  }
  __shared__ float sm[1024], ss[1024];
  sm[tid] = m; ss[tid] = s;
  __syncthreads();
  for (int st = 512; st > 0; st >>= 1) {
    if (tid < st) {
      float m2 = sm[tid + st], s2 = ss[tid + st];
      float mn = fmaxf(sm[tid], m2);
      ss[tid] = ss[tid] * expf(sm[tid] - mn) + s2 * expf(m2 - mn);
      sm[tid] = mn;
    }
    __syncthreads();
  }
  float L = logf(ss[0]) + sm[0];
  for (int i = tid; i < V_; i += 1024) x[i] = x[i] - L;
}

extern "C" void kernel_launch(void* const* d_in, const int* in_sizes, int n_in,
                              void* d_out, int out_size, void* d_ws, size_t ws_size,
                              hipStream_t stream) {
  const int*   inputs  = (const int*)d_in[0];
  const float* enc_h   = (const float*)d_in[1];
  const float* enc_out = (const float*)d_in[2];
  const float* emb     = (const float*)d_in[3];
  const float* W_ih    = (const float*)d_in[4];
  const float* W_hh    = (const float*)d_in[5];
  const float* b_ih    = (const float*)d_in[6];
  const float* b_hh    = (const float*)d_in[7];
  const float* attn_W  = (const float*)d_in[8];
  const float* attn_b  = (const float*)d_in[9];
  const float* out_W   = (const float*)d_in[10];
  const float* out_b   = (const float*)d_in[11];

  float* out       = (float*)d_out;
  float* log_probs = out;
  float* hlast     = out + (size_t)B_ * T_ * V_;
  float* attn      = hlast + B_ * H_;

  char* wsb = (char*)d_ws;
  // full-path layout (bytes)
  const size_t OFF_BAR   = 0;                                      // 4 KB flags
  const size_t OFF_OUTWB = 4096;
  const size_t OFF_XB    = OFF_OUTWB + (size_t)V_ * H_ * 2;
  const size_t OFF_XG    = OFF_XB + (size_t)1024 * H_ * 2;
  const size_t OFF_GRU   = OFF_XG + (size_t)1024 * G_ * 4;
  const size_t OFF_CB    = OFF_GRU + (size_t)1024 * H_ * 4;
  const size_t OFF_O2B   = OFF_CB + (size_t)1024 * 1024 * 2;
  const size_t OFF_WIHB  = OFF_O2B + (size_t)1024 * H_ * 2;
  const size_t OFF_AWB   = OFF_WIHB + (size_t)G_ * H_ * 2;
  const size_t NEED_FULL = OFF_AWB + (size_t)H_ * 1024 * 2;        // ~45.8MB

  if (ws_size >= NEED_FULL) {
    u32*     bar    = (u32*)(wsb + OFF_BAR);
    __bf16*  outWb  = (__bf16*)(wsb + OFF_OUTWB);
    __bf16*  Xb     = (__bf16*)(wsb + OFF_XB);
    float*   xg     = (float*)(wsb + OFF_XG);
    float*   gru    = (float*)(wsb + OFF_GRU);
    __bf16*  combb  = (__bf16*)(wsb + OFF_CB);
    __bf16*  out2b  = (__bf16*)(wsb + OFF_O2B);
    __bf16*  Wihb   = (__bf16*)(wsb + OFF_WIHB);
    __bf16*  aWb    = (__bf16*)(wsb + OFF_AWB);

    k_zero<<<1, 1024, 0, stream>>>(bar);
    k_cast<<<2048, 256, 0, stream>>>(out_W, outWb, V_ * H_ / 4);
    k_cast<<<256, 256, 0, stream>>>(W_ih, Wihb, G_ * H_ / 4);
    k_cast<<<256, 256, 0, stream>>>(attn_W, aWb, H_ * 1024 / 4);
    k_gather_bf<<<1024, 128, 0, stream>>>(inputs, emb, Xb);
    // xg = X @ W_ih^T + b_ih   (M=1024, N=1536, K=512)
    k_gemm_bf16<0, 1, 0><<<96, 256, 0, stream>>>(Xb, Wihb, b_ih, xg, (__bf16*)0,
                                                 1024, G_, H_, 8, 0);
    k_gru_scan<<<NBLK_GRU, 384, 0, stream>>>(enc_h, xg, W_hh, b_hh, gru, bar);
    k_hlast<<<32, 256, 0, stream>>>(gru, hlast);
    k_attn<0, 1><<<1024, 256, 0, stream>>>(gru, enc_out, attn, (float*)0, combb);
    // out2 = tanh(combined @ attn_W^T + attn_b)  (M=1024, N=512, K=1024) -> bf16 only
    k_gemm_bf16<1, 0, 1><<<32, 256, 0, stream>>>(combb, aWb, attn_b, (float*)0,
                                                 out2b, 1024, H_, 1024, 8, 0);
    // logits = out2 @ out_W^T + out_b  (M=1024, N=32000, K=512), XCD-grouped grid
    k_gemm_bf16<0, 1, 0><<<2048, 256, 0, stream>>>(out2b, outWb, out_b, log_probs,
                                                   (__bf16*)0, 1024, V_, H_, 8, 1);
    k_logsoftmax<<<1024, 1024, 0, stream>>>(log_probs);
  } else {
    // legacy tier: round-2 layout (8MB) + persistent GRU (flags in dead out2 region)
    float* ws       = (float*)d_ws;
    float* X        = ws;
    float* xg       = ws + 524288;
    float* gru      = ws;
    float* combined = ws + 524288;
    float* out2     = ws + 1572864;
    u32*   bar      = (u32*)(ws + 1572864);   // dead until attnproj

    k_zero<<<1, 1024, 0, stream>>>(bar);
    k_gather32<<<1024, 128, 0, stream>>>(inputs, emb, X);
    k_gemm<0><<<dim3(8, 12), 256, 0, stream>>>(X, W_ih, b_ih, xg, 1024, G_, H_);
    k_gru_scan<<<NBLK_GRU, 384, 0, stream>>>(enc_h, xg, W_hh, b_hh, gru, bar);
    k_hlast<<<32, 256, 0, stream>>>(gru, hlast);
    k_attn<1, 0><<<1024, 256, 0, stream>>>(gru, enc_out, attn, combined, (__bf16*)0);
    k_gemm<1><<<dim3(8, 4), 256, 0, stream>>>(combined, attn_W, attn_b, out2,
                                              1024, H_, 2 * H_);
    k_gemm<0><<<dim3(8, 250), 256, 0, stream>>>(out2, out_W, out_b, log_probs,
                                                1024, V_, H_);
    k_logsoftmax<<<1024, 1024, 0, stream>>>(log_probs);
  }
}